// Round 11
// baseline (145.653 us; speedup 1.0000x reference)
//
#include <hip/hip_runtime.h>
#include <stdint.h>

#define LL 4096
#define NB 2
#define KK 30
#define CDIM 128
#define FROW 200  // feat row stride in halves (400 B, multiple of 16 B)

typedef _Float16 half_t;
typedef half_t half8 __attribute__((ext_vector_type(8)));
typedef float f32x4 __attribute__((ext_vector_type(4)));

__device__ __forceinline__ float3 loadCa(const float* __restrict__ Ca, int b, int idx) {
    const float* p = Ca + ((size_t)(b * LL + idx)) * 3;
    return make_float3(p[0], p[1], p[2]);
}
__device__ __forceinline__ float3 shiftedCa(const float* __restrict__ Ca, int b, int idx, int sel) {
    int jj = idx + sel - 1;
    if (jj < 0 || jj >= LL) return make_float3(0.f, 0.f, 0.f);
    return loadCa(Ca, b, jj);
}
__device__ __forceinline__ float sgnf(float x) { return (x > 0.f) ? 1.f : ((x < 0.f) ? -1.f : 0.f); }
__device__ __forceinline__ float pdist(float3 a, float3 c) {
    float dx = a.x - c.x, dy = a.y - c.y, dz = a.z - c.z;
    return sqrtf(dx * dx + dy * dy + dz * dz + 1e-6f);
}

// ---------------- prep: W pack (f16 B-frags) + posW transpose + local frames ----------------
__global__ __launch_bounds__(256) void prep_kernel(const float* __restrict__ W,
                                                   const float* __restrict__ posW,
                                                   const float* __restrict__ posb,
                                                   const float* __restrict__ Ca,
                                                   half_t* __restrict__ Bp,
                                                   half_t* __restrict__ pwt,
                                                   float* __restrict__ Of) {
    int blk = blockIdx.x;
    int tid = threadIdx.x;
    if (blk < 12) {
        // Bp[((t*6+s)*64 + l)*8 + e] = W[n=16t+(l&15)][k=32s+8*(l>>4)+e], 0 if k>=167
        int idx = blk * 256 + tid;
        if (idx >= 8 * 6 * 64) return;
        int l = idx & 63;
        int ts = idx >> 6;
        int s = ts % 6, t = ts / 6;
        int n = 16 * t + (l & 15);
        int kbase = 32 * s + 8 * (l >> 4);
        half8 v;
#pragma unroll
        for (int e = 0; e < 8; e++) {
            int k = kbase + e;
            v[e] = (k < 167) ? (half_t)W[n * 167 + k] : (half_t)0.f;
        }
        *(half8*)(Bp + (size_t)idx * 8) = v;
    } else if (blk < 17) {
        int idx = (blk - 12) * 256 + tid;
        if (idx < 66 * 16) {
            int d = idx >> 4, p = idx & 15;
            pwt[d * 16 + p] = (half_t)(posW[p * 66 + d] + posb[p]);
        }
    } else {
        int t = (blk - 17) * 256 + tid;
        if (t >= NB * LL) return;
        int b = t >> 12, i = t & (LL - 1);
        float o[9] = {0.f, 0.f, 0.f, 0.f, 0.f, 0.f, 0.f, 0.f, 0.f};
        if (i >= 1 && i <= LL - 3) {
            float3 cm = loadCa(Ca, b, i - 1), cc = loadCa(Ca, b, i), cp = loadCa(Ca, b, i + 1);
            float dx0 = cc.x - cm.x, dy0 = cc.y - cm.y, dz0 = cc.z - cm.z;
            float n0 = sqrtf(dx0 * dx0 + dy0 * dy0 + dz0 * dz0);
            float k0 = (n0 > 3.6f && n0 < 4.0f) ? 1.f : 0.f;
            float s0 = k0 / fmaxf(n0 * k0, 1e-12f);
            float u2x = dx0 * s0, u2y = dy0 * s0, u2z = dz0 * s0;
            float dx1 = cp.x - cc.x, dy1 = cp.y - cc.y, dz1 = cp.z - cc.z;
            float n1 = sqrtf(dx1 * dx1 + dy1 * dy1 + dz1 * dz1);
            float k1 = (n1 > 3.6f && n1 < 4.0f) ? 1.f : 0.f;
            float s1 = k1 / fmaxf(n1 * k1, 1e-12f);
            float u1x = dx1 * s1, u1y = dy1 * s1, u1z = dz1 * s1;
            float cx = u2y * u1z - u2z * u1y;
            float cy = u2z * u1x - u2x * u1z;
            float cz = u2x * u1y - u2y * u1x;
            float cn = sqrtf(cx * cx + cy * cy + cz * cz);
            float cinv = 1.f / fmaxf(cn, 1e-12f);
            float n2x = cx * cinv, n2y = cy * cinv, n2z = cz * cinv;
            float ox = u2x - u1x, oy = u2y - u1y, oz = u2z - u1z;
            float on = sqrtf(ox * ox + oy * oy + oz * oz);
            float oinv = 1.f / fmaxf(on, 1e-12f);
            float o1x = ox * oinv, o1y = oy * oinv, o1z = oz * oinv;
            o[0] = o1x; o[1] = o1y; o[2] = o1z;
            o[3] = n2x; o[4] = n2y; o[5] = n2z;
            o[6] = o1y * n2z - o1z * n2y;
            o[7] = o1z * n2x - o1x * n2z;
            o[8] = o1x * n2y - o1y * n2x;
        }
        float* dst = Of + (size_t)t * 9;
#pragma unroll
        for (int r = 0; r < 9; r++) dst[r] = o[r];
    }
}

// ---------------- top-K per row: wave-local rank-select (no barriers) + merge ----------------
__global__ __launch_bounds__(256, 8) void topk_kernel(const float* __restrict__ Ca,
                                                      const float* __restrict__ mask,
                                                      int* __restrict__ eidx_ws,
                                                      float* __restrict__ dnb_ws,
                                                      float* __restrict__ out_eidx_f) {
    __shared__ unsigned long long wcand[4][64];  // per-wave candidate strip (wave-sync use)
    __shared__ unsigned long long wtop[4 * KK];  // per-wave sorted top-30
    __shared__ float wflt[4];
    int row = blockIdx.x;
    int b = row >> 12;
    int tid = threadIdx.x;
    int w = tid >> 6, lane = tid & 63;
    float3 ci = loadCa(Ca, b, row & (LL - 1));
    float mi = mask[row];
    float dreg[16];
    float localmax = 0.f;
#pragma unroll
    for (int s = 0; s < 16; s++) {
        int j = tid + s * 256;
        const float* pj = Ca + ((size_t)(b * LL + j)) * 3;
        float dx = pj[0] - ci.x, dy = pj[1] - ci.y, dz = pj[2] - ci.z;
        float d = sqrtf(dx * dx + dy * dy + dz * dz + 1e-6f);
        float D = mi * mask[b * LL + j] * d;
        dreg[s] = D;
        localmax = fmaxf(localmax, D);
    }
#pragma unroll
    for (int o = 32; o; o >>= 1) localmax = fmaxf(localmax, __shfl_xor(localmax, o));
    if (lane == 0) wflt[w] = localmax;
    __syncthreads();
    float dmax = fmaxf(fmaxf(wflt[0], wflt[1]), fmaxf(wflt[2], wflt[3]));
    // dadj bits (positive floats -> uint order == value order)
    unsigned ui[16];
#pragma unroll
    for (int s = 0; s < 16; s++) {
        int j = tid + s * 256;
        float m2 = mi * mask[b * LL + j];
        ui[s] = __float_as_uint(dreg[s] + (1.0f - m2) * dmax);
    }
    // wave-local binary search over this wave's 1024 elems: count(bits<T) in [30,64].
    // Shuffle-only reduction -> ZERO block barriers in this loop.
    unsigned lo = 0u, hi = __float_as_uint(dmax) + 1u, T = 0u;
    bool found = false;
    for (int it = 0; it < 24 && !found && (hi - lo) > 1u; ++it) {
        unsigned mid = (lo + hi) >> 1;
        int c = 0;
#pragma unroll
        for (int s = 0; s < 16; s++) c += (ui[s] < mid) ? 1 : 0;
#pragma unroll
        for (int o = 32; o; o >>= 1) c += __shfl_xor(c, o);
        if (c < 30) lo = mid;
        else if (c > 64) hi = mid;
        else { T = mid; found = true; }
    }
    if (!found) T = hi;
    int cnt = 0;
#pragma unroll
    for (int s = 0; s < 16; s++) cnt += (ui[s] < T) ? 1 : 0;
    int inc = cnt;
#pragma unroll
    for (int o = 1; o < 64; o <<= 1) {
        int nv = __shfl_up(inc, o);
        if (lane >= o) inc += nv;
    }
    int C = __shfl(inc, 63);  // wave total
    if (C <= 64) {
        // gather into this wave's LDS strip (wave-synchronous), bitonic sort 64
        int slot = inc - cnt;
#pragma unroll
        for (int s = 0; s < 16; s++) {
            if (ui[s] < T) {
                int j = tid + s * 256;
                if (slot < 64)
                    wcand[w][slot] = ((unsigned long long)ui[s] << 32) | (unsigned)j;
                slot++;
            }
        }
        unsigned long long v = (lane < C) ? wcand[w][lane] : ~0ull;
#pragma unroll
        for (int k = 2; k <= 64; k <<= 1) {
#pragma unroll
            for (int jj = k >> 1; jj > 0; jj >>= 1) {
                unsigned long long o = __shfl_xor(v, jj);
                bool take_min = (((lane & jj) == 0) == ((lane & k) == 0));
                bool lt = (o < v);
                v = (take_min == lt) ? o : v;
            }
        }
        if (lane < KK) wtop[w * KK + lane] = v;
    } else {
        // rare (needs >=35 bit-identical keys): wave-local serial extract-min
        for (int t = 0; t < KK; ++t) {
            unsigned long long v = ~0ull;
#pragma unroll
            for (int s = 0; s < 16; s++) {
                unsigned long long k = ((unsigned long long)ui[s] << 32) | (unsigned)(tid + s * 256);
                if (k < v) v = k;
            }
#pragma unroll
            for (int o = 32; o; o >>= 1) {
                unsigned long long u = __shfl_xor(v, o);
                if (u < v) v = u;
            }
#pragma unroll
            for (int s = 0; s < 16; s++) {
                unsigned long long k = ((unsigned long long)ui[s] << 32) | (unsigned)(tid + s * 256);
                if (k == v) ui[s] = 0xFFFFFFFFu;  // evict (larger than any finite key)
            }
            if (lane == 0) wtop[w * KK + t] = v;
        }
    }
    __syncthreads();
    if (w != 0) return;
    // wave 0: merge 120 candidates (global top-30 is a subset of the per-wave top-30s)
    unsigned long long r0 = (lane < 4 * KK) ? wtop[lane] : ~0ull;
    unsigned long long r1 = (lane + 64 < 4 * KK) ? wtop[lane + 64] : ~0ull;
    for (int t = 0; t < KK; ++t) {
        unsigned long long v = (r0 < r1) ? r0 : r1;
#pragma unroll
        for (int o = 32; o; o >>= 1) {
            unsigned long long u = __shfl_xor(v, o);
            if (u < v) v = u;
        }
        if (lane == 0) {
            int j = (int)(v & 0xffffffffu);
            eidx_ws[row * KK + t] = j;
            dnb_ws[row * KK + t] = __uint_as_float((unsigned)(v >> 32));
            out_eidx_f[row * KK + t] = (float)j;
        }
        if (r0 == v) r0 = ~0ull;
        if (r1 == v) r1 = ~0ull;
    }
}

// ---------------- features + col-split MFMA + stats-only LN epilogue ----------------
__global__ __launch_bounds__(256) void edge_kernel(const float* __restrict__ Ca,
                                                   const int* __restrict__ ridx,
                                                   const int* __restrict__ chl,
                                                   const half_t* __restrict__ pwt,
                                                   const half_t* __restrict__ Bp,
                                                   const float* __restrict__ ln_g,
                                                   const float* __restrict__ ln_b,
                                                   const float* __restrict__ Of,
                                                   const int* __restrict__ eidx_ws,
                                                   const float* __restrict__ dnb_ws,
                                                   float* __restrict__ outE) {
    __shared__ alignas(16) half_t featH[64][FROW];
    __shared__ float sD[60][10];
    __shared__ float psum[64][4];  // per-row LN partial sums, one col-slice per wave
    __shared__ float pssq[64][4];
    __shared__ float rmu[64], rinv[64];
    int row0 = blockIdx.x * 2;
    int b = row0 >> 12;
    int tid = threadIdx.x;

    // P0: 2 threads per edge — load points once, compute 9 distances + pos + orient.
    // Threads 156..255 zero rows 60..63 (stale LDS otherwise feeds A-frags on replay).
    if (tid < 120) {
        int e = tid >> 1, half = tid & 1;
        int isr1 = (e >= KK) ? 1 : 0;
        int grow = row0 + isr1;
        int ke = e - (isr1 ? KK : 0);
        int i = grow & (LL - 1);
        int j = eidx_ws[grow * KK + ke];
        if (half == 0) {
            float3 Pi0 = shiftedCa(Ca, b, i, 0);
            float3 Pi2 = shiftedCa(Ca, b, i, 2);
            float3 Pj0 = shiftedCa(Ca, b, j, 0);
            float3 Pj1 = loadCa(Ca, b, j);
            float3 Pj2 = shiftedCa(Ca, b, j, 2);
            sD[e][0] = dnb_ws[grow * KK + ke];
            sD[e][1] = pdist(Pi0, Pj0);
            sD[e][2] = pdist(Pi2, Pj2);
            sD[e][3] = pdist(Pi0, Pj1);
            sD[e][4] = pdist(Pi0, Pj2);
            int off = ridx[grow] - ridx[b * LL + j];
            int eqc = (chl[grow] == chl[b * LL + j]) ? 1 : 0;
            int d = off + 32;
            d = d < 0 ? 0 : (d > 64 ? 64 : d);
            d = eqc ? d : 65;
            *(half8*)&featH[e][0] = *(const half8*)(pwt + d * 16);
            *(half8*)&featH[e][8] = *(const half8*)(pwt + d * 16 + 8);
        } else {
            float3 Pi1 = loadCa(Ca, b, i);
            float3 Pi2 = shiftedCa(Ca, b, i, 2);
            float3 Pj0 = shiftedCa(Ca, b, j, 0);
            float3 Pj1 = loadCa(Ca, b, j);
            float3 Pj2 = shiftedCa(Ca, b, j, 2);
            sD[e][5] = pdist(Pi1, Pj0);
            sD[e][6] = pdist(Pi1, Pj2);
            sD[e][7] = pdist(Pi2, Pj0);
            sD[e][8] = pdist(Pi2, Pj1);
            float Oi[9], Oj[9];
#pragma unroll
            for (int r = 0; r < 9; r++) {
                Oi[r] = Of[(size_t)grow * 9 + r];
                Oj[r] = Of[((size_t)(b * LL + j)) * 9 + r];
            }
            float dx = Pj1.x - Pi1.x, dy = Pj1.y - Pi1.y, dz = Pj1.z - Pi1.z;
            float v0 = Oi[0] * dx + Oi[1] * dy + Oi[2] * dz;
            float v1 = Oi[3] * dx + Oi[4] * dy + Oi[5] * dz;
            float v2 = Oi[6] * dx + Oi[7] * dy + Oi[8] * dz;
            float nn = sqrtf(v0 * v0 + v1 * v1 + v2 * v2);
            float ninv = 1.f / fmaxf(nn, 1e-12f);
            float R[3][3];
#pragma unroll
            for (int m = 0; m < 3; m++)
#pragma unroll
                for (int n = 0; n < 3; n++)
                    R[m][n] = Oi[0 * 3 + m] * Oj[0 * 3 + n] + Oi[1 * 3 + m] * Oj[1 * 3 + n] +
                              Oi[2 * 3 + m] * Oj[2 * 3 + n];
            float Rxx = R[0][0], Ryy = R[1][1], Rzz = R[2][2];
            float m0 = 0.5f * sqrtf(fabsf(1.f + Rxx - Ryy - Rzz));
            float m1 = 0.5f * sqrtf(fabsf(1.f - Rxx + Ryy - Rzz));
            float m2 = 0.5f * sqrtf(fabsf(1.f - Rxx - Ryy + Rzz));
            float x = sgnf(R[2][1] - R[1][2]) * m0;
            float y = sgnf(R[0][2] - R[2][0]) * m1;
            float z = sgnf(R[1][0] - R[0][1]) * m2;
            float ww = 0.5f * sqrtf(fmaxf(1.f + Rxx + Ryy + Rzz, 0.f));
            float qn = sqrtf(x * x + y * y + z * z + ww * ww);
            float qi = 1.f / fmaxf(qn, 1e-12f);
            half8 h;
            h[0] = (half_t)(v0 * ninv);
            h[1] = (half_t)(v1 * ninv);
            h[2] = (half_t)(v2 * ninv);
            h[3] = (half_t)(x * qi);
            h[4] = (half_t)(y * qi);
            h[5] = (half_t)(z * qi);
            h[6] = (half_t)(ww * qi);
            h[7] = (half_t)0.f;
            half8 zv = {};
            *(half8*)&featH[e][160] = h;   // cols 160..167 (167 = 0)
            *(half8*)&featH[e][168] = zv;  // zero k-pad; MFMA reads up to col 192
            *(half8*)&featH[e][176] = zv;
            *(half8*)&featH[e][184] = zv;
        }
    } else if (tid >= 156) {
        int t = tid - 156;  // 0..99: zero rows 60..63 (25 half8 chunks each)
        int r = 60 + t / 25, c = t % 25;
        half8 zv = {};
        *(half8*)&featH[r][c * 8] = zv;
    }
    __syncthreads();

    // P1: 540 uniform RBF jobs (edge x group), LDS-only inputs
    for (int job = tid; job < 540; job += 256) {
        int e = job / 9, q = job - e * 9;
        float D = sD[e][q];
        half8 v0, v1;
#pragma unroll
        for (int m = 0; m < 8; m++) {
            float mu = 2.0f + (4.f / 3.f) * (float)m;
            float t = (D - mu) * 0.8f;
            v0[m] = (half_t)exp2f(t * t * -1.4426950408889634f);
        }
#pragma unroll
        for (int m = 8; m < 16; m++) {
            float mu = 2.0f + (4.f / 3.f) * (float)m;
            float t = (D - mu) * 0.8f;
            v1[m - 8] = (half_t)exp2f(t * t * -1.4426950408889634f);
        }
        *(half8*)&featH[e][16 + 16 * q] = v0;
        *(half8*)&featH[e][24 + 16 * q] = v1;
    }
    __syncthreads();

    // P2: col-split MFMA — wave w owns all 64 rows x cols [32w, 32w+32)
    int lane = tid & 63, w = tid >> 6;
    int cc = lane & 15, g = lane >> 4;
    f32x4 zero = {0.f, 0.f, 0.f, 0.f};
    f32x4 acc[4][2];
#pragma unroll
    for (int m = 0; m < 4; m++) {
        acc[m][0] = zero;
        acc[m][1] = zero;
    }
    const half_t* b0p = Bp + ((size_t)(2 * w) * 6) * 64 * 8;
    const half_t* b1p = Bp + ((size_t)(2 * w + 1) * 6) * 64 * 8;
    for (int s = 0; s < 6; s++) {
        int ko = 32 * s + 8 * g;
        half8 af0 = *(const half8*)&featH[cc][ko];
        half8 af1 = *(const half8*)&featH[16 + cc][ko];
        half8 af2 = *(const half8*)&featH[32 + cc][ko];
        half8 af3 = *(const half8*)&featH[48 + cc][ko];
        half8 bf0 = *(const half8*)(b0p + (size_t)(s * 64 + lane) * 8);
        half8 bf1 = *(const half8*)(b1p + (size_t)(s * 64 + lane) * 8);
        acc[0][0] = __builtin_amdgcn_mfma_f32_16x16x32_f16(af0, bf0, acc[0][0], 0, 0, 0);
        acc[0][1] = __builtin_amdgcn_mfma_f32_16x16x32_f16(af0, bf1, acc[0][1], 0, 0, 0);
        acc[1][0] = __builtin_amdgcn_mfma_f32_16x16x32_f16(af1, bf0, acc[1][0], 0, 0, 0);
        acc[1][1] = __builtin_amdgcn_mfma_f32_16x16x32_f16(af1, bf1, acc[1][1], 0, 0, 0);
        acc[2][0] = __builtin_amdgcn_mfma_f32_16x16x32_f16(af2, bf0, acc[2][0], 0, 0, 0);
        acc[2][1] = __builtin_amdgcn_mfma_f32_16x16x32_f16(af2, bf1, acc[2][1], 0, 0, 0);
        acc[3][0] = __builtin_amdgcn_mfma_f32_16x16x32_f16(af3, bf0, acc[3][0], 0, 0, 0);
        acc[3][1] = __builtin_amdgcn_mfma_f32_16x16x32_f16(af3, bf1, acc[3][1], 0, 0, 0);
    }

    // P3: per-row LN partials within the wave's 32-col slice -> psum/pssq[row][w]
#pragma unroll
    for (int m = 0; m < 4; m++) {
#pragma unroll
        for (int q = 0; q < 4; q++) {
            float v0 = acc[m][0][q], v1 = acc[m][1][q];
            float sp = v0 + v1;
            float qp = v0 * v0 + v1 * v1;
#pragma unroll
            for (int o = 1; o < 16; o <<= 1) {
                sp += __shfl_xor(sp, o);
                qp += __shfl_xor(qp, o);
            }
            if (cc == 0) {
                int r = 16 * m + 4 * g + q;
                psum[r][w] = sp;
                pssq[r][w] = qp;
            }
        }
    }
    __syncthreads();
    if (tid < 64) {
        float sum = psum[tid][0] + psum[tid][1] + psum[tid][2] + psum[tid][3];
        float ssq = pssq[tid][0] + pssq[tid][1] + pssq[tid][2] + pssq[tid][3];
        float mu = sum * (1.f / 128.f);
        float var = fmaxf(ssq * (1.f / 128.f) - mu * mu, 0.f);
        rmu[tid] = mu;
        rinv[tid] = 1.f / sqrtf(var + 1e-5f);
    }
    __syncthreads();

    // P4: normalize + store directly from registers
    float lgv[2], lbv[2];
#pragma unroll
    for (int tt = 0; tt < 2; tt++) {
        lgv[tt] = ln_g[32 * w + 16 * tt + cc];
        lbv[tt] = ln_b[32 * w + 16 * tt + cc];
    }
#pragma unroll
    for (int m = 0; m < 4; m++) {
#pragma unroll
        for (int q = 0; q < 4; q++) {
            int r = 16 * m + 4 * g + q;
            if (r < 60) {
                float mu = rmu[r], invs = rinv[r];
                int grow = row0 + (r >= KK ? 1 : 0);
                int ke = r - (r >= KK ? KK : 0);
                float* dst = outE + ((size_t)(grow * KK + ke)) * CDIM + 32 * w + cc;
                dst[0] = (acc[m][0][q] - mu) * invs * lgv[0] + lbv[0];
                dst[16] = (acc[m][1][q] - mu) * invs * lgv[1] + lbv[1];
            }
        }
    }
}

extern "C" void kernel_launch(void* const* d_in, const int* in_sizes, int n_in,
                              void* d_out, int out_size, void* d_ws, size_t ws_size,
                              hipStream_t stream) {
    const float* Ca = (const float*)d_in[0];
    const float* mask = (const float*)d_in[1];
    const int* ridx = (const int*)d_in[2];
    const int* chl = (const int*)d_in[3];
    const float* posW = (const float*)d_in[4];
    const float* posb = (const float*)d_in[5];
    const float* edgeW = (const float*)d_in[6];
    const float* lng = (const float*)d_in[7];
    const float* lnb = (const float*)d_in[8];

    float* outE = (float*)d_out;
    float* outEidxF = outE + (size_t)NB * LL * KK * CDIM;

    char* ws = (char*)d_ws;
    half_t* Bp = (half_t*)ws;                     // 49152 B
    half_t* pwt = (half_t*)(ws + 49152);          // 2112 B
    float* Of = (float*)(ws + 51264);             // 294912 B
    int* eidx = (int*)(ws + 346176);              // 983040 B
    float* dnb = (float*)(ws + 1329216);          // 983040 B

    prep_kernel<<<17 + (NB * LL + 255) / 256, 256, 0, stream>>>(edgeW, posW, posb, Ca, Bp, pwt, Of);
    topk_kernel<<<NB * LL, 256, 0, stream>>>(Ca, mask, eidx, dnb, outEidxF);
    edge_kernel<<<NB * LL / 2, 256, 0, stream>>>(Ca, ridx, chl, pwt, Bp, lng, lnb,
                                                 Of, eidx, dnb, outE);
}

// Round 12
// 120.126 us; speedup vs baseline: 1.2125x; 1.2125x over previous
//
#include <hip/hip_runtime.h>
#include <stdint.h>

#define LL 4096
#define NB 2
#define KK 30
#define CDIM 128
#define FROW 200  // feat row stride in halves (400 B, multiple of 16 B)

typedef _Float16 half_t;
typedef half_t half8 __attribute__((ext_vector_type(8)));
typedef float f32x4 __attribute__((ext_vector_type(4)));

__device__ __forceinline__ float3 loadCa(const float* __restrict__ Ca, int b, int idx) {
    const float* p = Ca + ((size_t)(b * LL + idx)) * 3;
    return make_float3(p[0], p[1], p[2]);
}
__device__ __forceinline__ float3 loadCa4(const f32x4* __restrict__ Ca4, int b, int idx) {
    f32x4 v = Ca4[b * LL + idx];
    return make_float3(v[0], v[1], v[2]);
}
__device__ __forceinline__ float3 shiftedCa4(const f32x4* __restrict__ Ca4, int b, int idx, int sel) {
    int jj = idx + sel - 1;
    if (jj < 0 || jj >= LL) return make_float3(0.f, 0.f, 0.f);
    return loadCa4(Ca4, b, jj);
}
__device__ __forceinline__ float sgnf(float x) { return (x > 0.f) ? 1.f : ((x < 0.f) ? -1.f : 0.f); }
__device__ __forceinline__ float pdist(float3 a, float3 c) {
    float dx = a.x - c.x, dy = a.y - c.y, dz = a.z - c.z;
    return sqrtf(dx * dx + dy * dy + dz * dz + 1e-6f);
}

// ------- prep: W pack (f16 B-frags) + posW transpose + local frames + Ca float4 copy -------
__global__ __launch_bounds__(256) void prep_kernel(const float* __restrict__ W,
                                                   const float* __restrict__ posW,
                                                   const float* __restrict__ posb,
                                                   const float* __restrict__ Ca,
                                                   half_t* __restrict__ Bp,
                                                   half_t* __restrict__ pwt,
                                                   float* __restrict__ Of,
                                                   f32x4* __restrict__ Ca4) {
    int blk = blockIdx.x;
    int tid = threadIdx.x;
    if (blk < 12) {
        // Bp[((t*6+s)*64 + l)*8 + e] = W[n=16t+(l&15)][k=32s+8*(l>>4)+e], 0 if k>=167
        int idx = blk * 256 + tid;
        if (idx >= 8 * 6 * 64) return;
        int l = idx & 63;
        int ts = idx >> 6;
        int s = ts % 6, t = ts / 6;
        int n = 16 * t + (l & 15);
        int kbase = 32 * s + 8 * (l >> 4);
        half8 v;
#pragma unroll
        for (int e = 0; e < 8; e++) {
            int k = kbase + e;
            v[e] = (k < 167) ? (half_t)W[n * 167 + k] : (half_t)0.f;
        }
        *(half8*)(Bp + (size_t)idx * 8) = v;
    } else if (blk < 17) {
        int idx = (blk - 12) * 256 + tid;
        if (idx < 66 * 16) {
            int d = idx >> 4, p = idx & 15;
            pwt[d * 16 + p] = (half_t)(posW[p * 66 + d] + posb[p]);
        }
    } else {
        int t = (blk - 17) * 256 + tid;
        if (t >= NB * LL) return;
        int b = t >> 12, i = t & (LL - 1);
        // float4-aligned Ca copy (vector loads downstream)
        f32x4 c4;
        c4[0] = Ca[(size_t)t * 3];
        c4[1] = Ca[(size_t)t * 3 + 1];
        c4[2] = Ca[(size_t)t * 3 + 2];
        c4[3] = 0.f;
        Ca4[t] = c4;
        float o[9] = {0.f, 0.f, 0.f, 0.f, 0.f, 0.f, 0.f, 0.f, 0.f};
        if (i >= 1 && i <= LL - 3) {
            float3 cm = loadCa(Ca, b, i - 1), cc = loadCa(Ca, b, i), cp = loadCa(Ca, b, i + 1);
            float dx0 = cc.x - cm.x, dy0 = cc.y - cm.y, dz0 = cc.z - cm.z;
            float n0 = sqrtf(dx0 * dx0 + dy0 * dy0 + dz0 * dz0);
            float k0 = (n0 > 3.6f && n0 < 4.0f) ? 1.f : 0.f;
            float s0 = k0 / fmaxf(n0 * k0, 1e-12f);
            float u2x = dx0 * s0, u2y = dy0 * s0, u2z = dz0 * s0;
            float dx1 = cp.x - cc.x, dy1 = cp.y - cc.y, dz1 = cp.z - cc.z;
            float n1 = sqrtf(dx1 * dx1 + dy1 * dy1 + dz1 * dz1);
            float k1 = (n1 > 3.6f && n1 < 4.0f) ? 1.f : 0.f;
            float s1 = k1 / fmaxf(n1 * k1, 1e-12f);
            float u1x = dx1 * s1, u1y = dy1 * s1, u1z = dz1 * s1;
            float cx = u2y * u1z - u2z * u1y;
            float cy = u2z * u1x - u2x * u1z;
            float cz = u2x * u1y - u2y * u1x;
            float cn = sqrtf(cx * cx + cy * cy + cz * cz);
            float cinv = 1.f / fmaxf(cn, 1e-12f);
            float n2x = cx * cinv, n2y = cy * cinv, n2z = cz * cinv;
            float ox = u2x - u1x, oy = u2y - u1y, oz = u2z - u1z;
            float on = sqrtf(ox * ox + oy * oy + oz * oz);
            float oinv = 1.f / fmaxf(on, 1e-12f);
            float o1x = ox * oinv, o1y = oy * oinv, o1z = oz * oinv;
            o[0] = o1x; o[1] = o1y; o[2] = o1z;
            o[3] = n2x; o[4] = n2y; o[5] = n2z;
            o[6] = o1y * n2z - o1z * n2y;
            o[7] = o1z * n2x - o1x * n2z;
            o[8] = o1x * n2y - o1y * n2x;
        }
        float* dst = Of + (size_t)t * 9;
#pragma unroll
        for (int r = 0; r < 9; r++) dst[r] = o[r];
    }
}

// ---------------- top-K per row: rank-select threshold + bitonic sort ----------------
// (search/gather/sort identical to the 3x-validated R10 version; only the load phase
//  changed: float4 Ca loads + mask kept in a register bitmask)
__global__ __launch_bounds__(256, 8) void topk_kernel(const f32x4* __restrict__ Ca4,
                                                      const float* __restrict__ mask,
                                                      int* __restrict__ eidx_ws,
                                                      float* __restrict__ dnb_ws,
                                                      float* __restrict__ out_eidx_f) {
    __shared__ unsigned long long cand[512];
    __shared__ int wint[2][4];
    __shared__ int gcnt[4];  // DEDICATED gather totals (reusing wint[0] races — R4/R5 bug)
    __shared__ float wflt[4];
    int row = blockIdx.x;
    int b = row >> 12;
    int tid = threadIdx.x;
    int w = tid >> 6, lane = tid & 63;
    float3 ci = loadCa4(Ca4, b, row & (LL - 1));
    float mi = mask[row];
    float dreg[16];
    unsigned mfl = 0;
    float localmax = 0.f;
#pragma unroll
    for (int s = 0; s < 16; s++) {
        int j = tid + s * 256;
        f32x4 pj = Ca4[b * LL + j];
        float dx = pj[0] - ci.x, dy = pj[1] - ci.y, dz = pj[2] - ci.z;
        float d = sqrtf(dx * dx + dy * dy + dz * dz + 1e-6f);
        float m2 = mi * mask[b * LL + j];
        float D = m2 * d;
        dreg[s] = D;
        mfl |= (m2 == 0.f ? 1u : 0u) << s;
        localmax = fmaxf(localmax, D);
    }
#pragma unroll
    for (int o = 32; o; o >>= 1) localmax = fmaxf(localmax, __shfl_xor(localmax, o));
    if (lane == 0) wflt[w] = localmax;
    __syncthreads();
    float dmax = fmaxf(fmaxf(wflt[0], wflt[1]), fmaxf(wflt[2], wflt[3]));
    // dadj bits (positive floats -> uint order == value order)
    unsigned ui[16];
#pragma unroll
    for (int s = 0; s < 16; s++)
        ui[s] = __float_as_uint(dreg[s] + (((mfl >> s) & 1) ? dmax : 0.f));
    // binary search for threshold T: count(bits < T) in [30, 64]
    unsigned lo = 0u, hi = 0x7f800000u, T = 0u;
    bool found = false;
    int p = 0;
    for (int it = 0; it < 24 && !found; ++it) {
        unsigned mid = (lo + hi) >> 1;
        int c = 0;
#pragma unroll
        for (int s = 0; s < 16; s++) c += (ui[s] < mid) ? 1 : 0;
#pragma unroll
        for (int o = 32; o; o >>= 1) c += __shfl_xor(c, o);
        if (lane == 0) wint[p][w] = c;
        __syncthreads();
        c = wint[p][0] + wint[p][1] + wint[p][2] + wint[p][3];
        p ^= 1;
        if (c < 30) lo = mid;
        else if (c > 64) hi = mid;
        else { T = mid; found = true; }
    }
    if (!found) T = hi;
    // gather candidates (bits < T) into LDS via block prefix scan
    int cnt = 0;
#pragma unroll
    for (int s = 0; s < 16; s++) cnt += (ui[s] < T) ? 1 : 0;
    int inc = cnt;
#pragma unroll
    for (int o = 1; o < 64; o <<= 1) {
        int nv = __shfl_up(inc, o);
        if (lane >= o) inc += nv;
    }
    if (lane == 63) gcnt[w] = inc;
    __syncthreads();
    int C = gcnt[0] + gcnt[1] + gcnt[2] + gcnt[3];
    int waveoff = 0;
    for (int q = 0; q < 4; q++) waveoff += (q < w) ? gcnt[q] : 0;
    int slot = waveoff + inc - cnt;
#pragma unroll
    for (int s = 0; s < 16; s++) {
        if (ui[s] < T) {
            int j = tid + s * 256;
            if (slot < 512)
                cand[slot] = ((unsigned long long)ui[s] << 32) | (unsigned)j;
            slot++;
        }
    }
    __syncthreads();
    if (w != 0) return;
    if (C <= 64) {
        unsigned long long v = (lane < C) ? cand[lane] : ~0ull;
#pragma unroll
        for (int k = 2; k <= 64; k <<= 1) {
#pragma unroll
            for (int jj = k >> 1; jj > 0; jj >>= 1) {
                unsigned long long o = __shfl_xor(v, jj);
                bool take_min = (((lane & jj) == 0) == ((lane & k) == 0));
                bool lt = (o < v);
                v = (take_min == lt) ? o : v;
            }
        }
        if (lane < KK) {
            int j = (int)(v & 0xffffffffu);
            eidx_ws[row * KK + lane] = j;
            dnb_ws[row * KK + lane] = __uint_as_float((unsigned)(v >> 32));
            out_eidx_f[row * KK + lane] = (float)j;
        }
    } else {
        unsigned long long r[8];
#pragma unroll
        for (int q = 0; q < 8; q++) {
            int idx = lane + 64 * q;
            r[q] = (idx < C && idx < 512) ? cand[idx] : ~0ull;
        }
        for (int t = 0; t < KK; t++) {
            unsigned long long v = r[0];
#pragma unroll
            for (int q = 1; q < 8; q++) v = (r[q] < v) ? r[q] : v;
#pragma unroll
            for (int o = 32; o; o >>= 1) {
                unsigned long long u = __shfl_xor(v, o);
                if (u < v) v = u;
            }
            if (lane == 0) {
                int j = (int)(v & 0xffffffffu);
                eidx_ws[row * KK + t] = j;
                dnb_ws[row * KK + t] = __uint_as_float((unsigned)(v >> 32));
                out_eidx_f[row * KK + t] = (float)j;
            }
#pragma unroll
            for (int q = 0; q < 8; q++)
                if (r[q] == v) r[q] = ~0ull;
        }
    }
}

// ---------------- features + col-split MFMA + stats-only LN epilogue ----------------
__global__ __launch_bounds__(256) void edge_kernel(const f32x4* __restrict__ Ca4,
                                                   const int* __restrict__ ridx,
                                                   const int* __restrict__ chl,
                                                   const half_t* __restrict__ pwt,
                                                   const half_t* __restrict__ Bp,
                                                   const float* __restrict__ ln_g,
                                                   const float* __restrict__ ln_b,
                                                   const float* __restrict__ Of,
                                                   const int* __restrict__ eidx_ws,
                                                   const float* __restrict__ dnb_ws,
                                                   float* __restrict__ outE) {
    __shared__ alignas(16) half_t featH[64][FROW];
    __shared__ float sD[60][10];
    __shared__ float psum[64][4];  // per-row LN partial sums, one col-slice per wave
    __shared__ float pssq[64][4];
    __shared__ float rmu[64], rinv[64];
    int row0 = blockIdx.x * 2;
    int b = row0 >> 12;
    int tid = threadIdx.x;

    // P0: 2 threads per edge — load points once, compute 9 distances + pos + orient.
    // Threads 156..255 zero rows 60..63 (stale LDS otherwise feeds A-frags on replay).
    if (tid < 120) {
        int e = tid >> 1, half = tid & 1;
        int isr1 = (e >= KK) ? 1 : 0;
        int grow = row0 + isr1;
        int ke = e - (isr1 ? KK : 0);
        int i = grow & (LL - 1);
        int j = eidx_ws[grow * KK + ke];
        if (half == 0) {
            float3 Pi0 = shiftedCa4(Ca4, b, i, 0);
            float3 Pi2 = shiftedCa4(Ca4, b, i, 2);
            float3 Pj0 = shiftedCa4(Ca4, b, j, 0);
            float3 Pj1 = loadCa4(Ca4, b, j);
            float3 Pj2 = shiftedCa4(Ca4, b, j, 2);
            sD[e][0] = dnb_ws[grow * KK + ke];
            sD[e][1] = pdist(Pi0, Pj0);
            sD[e][2] = pdist(Pi2, Pj2);
            sD[e][3] = pdist(Pi0, Pj1);
            sD[e][4] = pdist(Pi0, Pj2);
            int off = ridx[grow] - ridx[b * LL + j];
            int eqc = (chl[grow] == chl[b * LL + j]) ? 1 : 0;
            int d = off + 32;
            d = d < 0 ? 0 : (d > 64 ? 64 : d);
            d = eqc ? d : 65;
            *(half8*)&featH[e][0] = *(const half8*)(pwt + d * 16);
            *(half8*)&featH[e][8] = *(const half8*)(pwt + d * 16 + 8);
        } else {
            float3 Pi1 = loadCa4(Ca4, b, i);
            float3 Pi2 = shiftedCa4(Ca4, b, i, 2);
            float3 Pj0 = shiftedCa4(Ca4, b, j, 0);
            float3 Pj1 = loadCa4(Ca4, b, j);
            float3 Pj2 = shiftedCa4(Ca4, b, j, 2);
            sD[e][5] = pdist(Pi1, Pj0);
            sD[e][6] = pdist(Pi1, Pj2);
            sD[e][7] = pdist(Pi2, Pj0);
            sD[e][8] = pdist(Pi2, Pj1);
            float Oi[9], Oj[9];
#pragma unroll
            for (int r = 0; r < 9; r++) {
                Oi[r] = Of[(size_t)grow * 9 + r];
                Oj[r] = Of[((size_t)(b * LL + j)) * 9 + r];
            }
            float dx = Pj1.x - Pi1.x, dy = Pj1.y - Pi1.y, dz = Pj1.z - Pi1.z;
            float v0 = Oi[0] * dx + Oi[1] * dy + Oi[2] * dz;
            float v1 = Oi[3] * dx + Oi[4] * dy + Oi[5] * dz;
            float v2 = Oi[6] * dx + Oi[7] * dy + Oi[8] * dz;
            float nn = sqrtf(v0 * v0 + v1 * v1 + v2 * v2);
            float ninv = 1.f / fmaxf(nn, 1e-12f);
            float R[3][3];
#pragma unroll
            for (int m = 0; m < 3; m++)
#pragma unroll
                for (int n = 0; n < 3; n++)
                    R[m][n] = Oi[0 * 3 + m] * Oj[0 * 3 + n] + Oi[1 * 3 + m] * Oj[1 * 3 + n] +
                              Oi[2 * 3 + m] * Oj[2 * 3 + n];
            float Rxx = R[0][0], Ryy = R[1][1], Rzz = R[2][2];
            float m0 = 0.5f * sqrtf(fabsf(1.f + Rxx - Ryy - Rzz));
            float m1 = 0.5f * sqrtf(fabsf(1.f - Rxx + Ryy - Rzz));
            float m2 = 0.5f * sqrtf(fabsf(1.f - Rxx - Ryy + Rzz));
            float x = sgnf(R[2][1] - R[1][2]) * m0;
            float y = sgnf(R[0][2] - R[2][0]) * m1;
            float z = sgnf(R[1][0] - R[0][1]) * m2;
            float ww = 0.5f * sqrtf(fmaxf(1.f + Rxx + Ryy + Rzz, 0.f));
            float qn = sqrtf(x * x + y * y + z * z + ww * ww);
            float qi = 1.f / fmaxf(qn, 1e-12f);
            half8 h;
            h[0] = (half_t)(v0 * ninv);
            h[1] = (half_t)(v1 * ninv);
            h[2] = (half_t)(v2 * ninv);
            h[3] = (half_t)(x * qi);
            h[4] = (half_t)(y * qi);
            h[5] = (half_t)(z * qi);
            h[6] = (half_t)(ww * qi);
            h[7] = (half_t)0.f;
            half8 zv = {};
            *(half8*)&featH[e][160] = h;   // cols 160..167 (167 = 0)
            *(half8*)&featH[e][168] = zv;  // zero k-pad; MFMA reads up to col 192
            *(half8*)&featH[e][176] = zv;
            *(half8*)&featH[e][184] = zv;
        }
    } else if (tid >= 156) {
        int t = tid - 156;  // 0..99: zero rows 60..63 (25 half8 chunks each)
        int r = 60 + t / 25, c = t % 25;
        half8 zv = {};
        *(half8*)&featH[r][c * 8] = zv;
    }
    __syncthreads();

    // P1: 540 uniform RBF jobs (edge x group), LDS-only inputs
    for (int job = tid; job < 540; job += 256) {
        int e = job / 9, q = job - e * 9;
        float D = sD[e][q];
        half8 v0, v1;
#pragma unroll
        for (int m = 0; m < 8; m++) {
            float mu = 2.0f + (4.f / 3.f) * (float)m;
            float t = (D - mu) * 0.8f;
            v0[m] = (half_t)exp2f(t * t * -1.4426950408889634f);
        }
#pragma unroll
        for (int m = 8; m < 16; m++) {
            float mu = 2.0f + (4.f / 3.f) * (float)m;
            float t = (D - mu) * 0.8f;
            v1[m - 8] = (half_t)exp2f(t * t * -1.4426950408889634f);
        }
        *(half8*)&featH[e][16 + 16 * q] = v0;
        *(half8*)&featH[e][24 + 16 * q] = v1;
    }
    __syncthreads();

    // P2: col-split MFMA — wave w owns all 64 rows x cols [32w, 32w+32)
    int lane = tid & 63, w = tid >> 6;
    int cc = lane & 15, g = lane >> 4;
    f32x4 zero = {0.f, 0.f, 0.f, 0.f};
    f32x4 acc[4][2];
#pragma unroll
    for (int m = 0; m < 4; m++) {
        acc[m][0] = zero;
        acc[m][1] = zero;
    }
    const half_t* b0p = Bp + ((size_t)(2 * w) * 6) * 64 * 8;
    const half_t* b1p = Bp + ((size_t)(2 * w + 1) * 6) * 64 * 8;
    for (int s = 0; s < 6; s++) {
        int ko = 32 * s + 8 * g;
        half8 af0 = *(const half8*)&featH[cc][ko];
        half8 af1 = *(const half8*)&featH[16 + cc][ko];
        half8 af2 = *(const half8*)&featH[32 + cc][ko];
        half8 af3 = *(const half8*)&featH[48 + cc][ko];
        half8 bf0 = *(const half8*)(b0p + (size_t)(s * 64 + lane) * 8);
        half8 bf1 = *(const half8*)(b1p + (size_t)(s * 64 + lane) * 8);
        acc[0][0] = __builtin_amdgcn_mfma_f32_16x16x32_f16(af0, bf0, acc[0][0], 0, 0, 0);
        acc[0][1] = __builtin_amdgcn_mfma_f32_16x16x32_f16(af0, bf1, acc[0][1], 0, 0, 0);
        acc[1][0] = __builtin_amdgcn_mfma_f32_16x16x32_f16(af1, bf0, acc[1][0], 0, 0, 0);
        acc[1][1] = __builtin_amdgcn_mfma_f32_16x16x32_f16(af1, bf1, acc[1][1], 0, 0, 0);
        acc[2][0] = __builtin_amdgcn_mfma_f32_16x16x32_f16(af2, bf0, acc[2][0], 0, 0, 0);
        acc[2][1] = __builtin_amdgcn_mfma_f32_16x16x32_f16(af2, bf1, acc[2][1], 0, 0, 0);
        acc[3][0] = __builtin_amdgcn_mfma_f32_16x16x32_f16(af3, bf0, acc[3][0], 0, 0, 0);
        acc[3][1] = __builtin_amdgcn_mfma_f32_16x16x32_f16(af3, bf1, acc[3][1], 0, 0, 0);
    }

    // P3: per-row LN partials within the wave's 32-col slice -> psum/pssq[row][w]
#pragma unroll
    for (int m = 0; m < 4; m++) {
#pragma unroll
        for (int q = 0; q < 4; q++) {
            float v0 = acc[m][0][q], v1 = acc[m][1][q];
            float sp = v0 + v1;
            float qp = v0 * v0 + v1 * v1;
#pragma unroll
            for (int o = 1; o < 16; o <<= 1) {
                sp += __shfl_xor(sp, o);
                qp += __shfl_xor(qp, o);
            }
            if (cc == 0) {
                int r = 16 * m + 4 * g + q;
                psum[r][w] = sp;
                pssq[r][w] = qp;
            }
        }
    }
    __syncthreads();
    if (tid < 64) {
        float sum = psum[tid][0] + psum[tid][1] + psum[tid][2] + psum[tid][3];
        float ssq = pssq[tid][0] + pssq[tid][1] + pssq[tid][2] + pssq[tid][3];
        float mu = sum * (1.f / 128.f);
        float var = fmaxf(ssq * (1.f / 128.f) - mu * mu, 0.f);
        rmu[tid] = mu;
        rinv[tid] = 1.f / sqrtf(var + 1e-5f);
    }
    __syncthreads();

    // P4: normalize + store directly from registers
    float lgv[2], lbv[2];
#pragma unroll
    for (int tt = 0; tt < 2; tt++) {
        lgv[tt] = ln_g[32 * w + 16 * tt + cc];
        lbv[tt] = ln_b[32 * w + 16 * tt + cc];
    }
#pragma unroll
    for (int m = 0; m < 4; m++) {
#pragma unroll
        for (int q = 0; q < 4; q++) {
            int r = 16 * m + 4 * g + q;
            if (r < 60) {
                float mu = rmu[r], invs = rinv[r];
                int grow = row0 + (r >= KK ? 1 : 0);
                int ke = r - (r >= KK ? KK : 0);
                float* dst = outE + ((size_t)(grow * KK + ke)) * CDIM + 32 * w + cc;
                dst[0] = (acc[m][0][q] - mu) * invs * lgv[0] + lbv[0];
                dst[16] = (acc[m][1][q] - mu) * invs * lgv[1] + lbv[1];
            }
        }
    }
}

extern "C" void kernel_launch(void* const* d_in, const int* in_sizes, int n_in,
                              void* d_out, int out_size, void* d_ws, size_t ws_size,
                              hipStream_t stream) {
    const float* Ca = (const float*)d_in[0];
    const float* mask = (const float*)d_in[1];
    const int* ridx = (const int*)d_in[2];
    const int* chl = (const int*)d_in[3];
    const float* posW = (const float*)d_in[4];
    const float* posb = (const float*)d_in[5];
    const float* edgeW = (const float*)d_in[6];
    const float* lng = (const float*)d_in[7];
    const float* lnb = (const float*)d_in[8];

    float* outE = (float*)d_out;
    float* outEidxF = outE + (size_t)NB * LL * KK * CDIM;

    char* ws = (char*)d_ws;
    half_t* Bp = (half_t*)ws;                     // 49152 B
    half_t* pwt = (half_t*)(ws + 49152);          // 2112 B
    float* Of = (float*)(ws + 51264);             // 294912 B
    int* eidx = (int*)(ws + 346176);              // 983040 B
    float* dnb = (float*)(ws + 1329216);          // 983040 B
    f32x4* Ca4 = (f32x4*)(ws + 2312256);          // 131072 B

    prep_kernel<<<17 + (NB * LL + 255) / 256, 256, 0, stream>>>(edgeW, posW, posb, Ca,
                                                                Bp, pwt, Of, Ca4);
    topk_kernel<<<NB * LL, 256, 0, stream>>>(Ca4, mask, eidx, dnb, outEidxF);
    edge_kernel<<<NB * LL / 2, 256, 0, stream>>>(Ca4, ridx, chl, pwt, Bp, lng, lnb,
                                                 Of, eidx, dnb, outE);
}

// Round 13
// 115.783 us; speedup vs baseline: 1.2580x; 1.0375x over previous
//
#include <hip/hip_runtime.h>
#include <stdint.h>

#define LL 4096
#define NB 2
#define KK 30
#define CDIM 128
#define FROW 200  // feat row stride in halves (400 B, multiple of 16 B)

typedef _Float16 half_t;
typedef half_t half8 __attribute__((ext_vector_type(8)));
typedef float f32x4 __attribute__((ext_vector_type(4)));

__device__ __forceinline__ float3 loadCa(const float* __restrict__ Ca, int b, int idx) {
    const float* p = Ca + ((size_t)(b * LL + idx)) * 3;
    return make_float3(p[0], p[1], p[2]);
}
__device__ __forceinline__ float3 loadCa4(const f32x4* __restrict__ Ca4, int b, int idx) {
    f32x4 v = Ca4[b * LL + idx];
    return make_float3(v[0], v[1], v[2]);
}
__device__ __forceinline__ float3 shiftedCa4(const f32x4* __restrict__ Ca4, int b, int idx, int sel) {
    int jj = idx + sel - 1;
    if (jj < 0 || jj >= LL) return make_float3(0.f, 0.f, 0.f);
    return loadCa4(Ca4, b, jj);
}
__device__ __forceinline__ float sgnf(float x) { return (x > 0.f) ? 1.f : ((x < 0.f) ? -1.f : 0.f); }
__device__ __forceinline__ float pdist(float3 a, float3 c) {
    float dx = a.x - c.x, dy = a.y - c.y, dz = a.z - c.z;
    return sqrtf(dx * dx + dy * dy + dz * dz + 1e-6f);
}

// ------- prep: W pack (f16 B-frags) + posW transpose + local frames + Ca float4 copy -------
__global__ __launch_bounds__(256) void prep_kernel(const float* __restrict__ W,
                                                   const float* __restrict__ posW,
                                                   const float* __restrict__ posb,
                                                   const float* __restrict__ Ca,
                                                   half_t* __restrict__ Bp,
                                                   half_t* __restrict__ pwt,
                                                   float* __restrict__ Of,
                                                   f32x4* __restrict__ Ca4) {
    int blk = blockIdx.x;
    int tid = threadIdx.x;
    if (blk < 12) {
        // Bp[((T*6+s)*64 + l)*8 + e] = W[n=16T+(l&15)][k=32s+8*(l>>4)+e], 0 if k>=167
        int idx = blk * 256 + tid;
        if (idx >= 8 * 6 * 64) return;
        int l = idx & 63;
        int ts = idx >> 6;
        int s = ts % 6, t = ts / 6;
        int n = 16 * t + (l & 15);
        int kbase = 32 * s + 8 * (l >> 4);
        half8 v;
#pragma unroll
        for (int e = 0; e < 8; e++) {
            int k = kbase + e;
            v[e] = (k < 167) ? (half_t)W[n * 167 + k] : (half_t)0.f;
        }
        *(half8*)(Bp + (size_t)idx * 8) = v;
    } else if (blk < 17) {
        int idx = (blk - 12) * 256 + tid;
        if (idx < 66 * 16) {
            int d = idx >> 4, p = idx & 15;
            pwt[d * 16 + p] = (half_t)(posW[p * 66 + d] + posb[p]);
        }
    } else {
        int t = (blk - 17) * 256 + tid;
        if (t >= NB * LL) return;
        int b = t >> 12, i = t & (LL - 1);
        f32x4 c4;
        c4[0] = Ca[(size_t)t * 3];
        c4[1] = Ca[(size_t)t * 3 + 1];
        c4[2] = Ca[(size_t)t * 3 + 2];
        c4[3] = 0.f;
        Ca4[t] = c4;
        float o[9] = {0.f, 0.f, 0.f, 0.f, 0.f, 0.f, 0.f, 0.f, 0.f};
        if (i >= 1 && i <= LL - 3) {
            float3 cm = loadCa(Ca, b, i - 1), cc = loadCa(Ca, b, i), cp = loadCa(Ca, b, i + 1);
            float dx0 = cc.x - cm.x, dy0 = cc.y - cm.y, dz0 = cc.z - cm.z;
            float n0 = sqrtf(dx0 * dx0 + dy0 * dy0 + dz0 * dz0);
            float k0 = (n0 > 3.6f && n0 < 4.0f) ? 1.f : 0.f;
            float s0 = k0 / fmaxf(n0 * k0, 1e-12f);
            float u2x = dx0 * s0, u2y = dy0 * s0, u2z = dz0 * s0;
            float dx1 = cp.x - cc.x, dy1 = cp.y - cc.y, dz1 = cp.z - cc.z;
            float n1 = sqrtf(dx1 * dx1 + dy1 * dy1 + dz1 * dz1);
            float k1 = (n1 > 3.6f && n1 < 4.0f) ? 1.f : 0.f;
            float s1 = k1 / fmaxf(n1 * k1, 1e-12f);
            float u1x = dx1 * s1, u1y = dy1 * s1, u1z = dz1 * s1;
            float cx = u2y * u1z - u2z * u1y;
            float cy = u2z * u1x - u2x * u1z;
            float cz = u2x * u1y - u2y * u1x;
            float cn = sqrtf(cx * cx + cy * cy + cz * cz);
            float cinv = 1.f / fmaxf(cn, 1e-12f);
            float n2x = cx * cinv, n2y = cy * cinv, n2z = cz * cinv;
            float ox = u2x - u1x, oy = u2y - u1y, oz = u2z - u1z;
            float on = sqrtf(ox * ox + oy * oy + oz * oz);
            float oinv = 1.f / fmaxf(on, 1e-12f);
            float o1x = ox * oinv, o1y = oy * oinv, o1z = oz * oinv;
            o[0] = o1x; o[1] = o1y; o[2] = o1z;
            o[3] = n2x; o[4] = n2y; o[5] = n2z;
            o[6] = o1y * n2z - o1z * n2y;
            o[7] = o1z * n2x - o1x * n2z;
            o[8] = o1x * n2y - o1y * n2x;
        }
        float* dst = Of + (size_t)t * 9;
#pragma unroll
        for (int r = 0; r < 9; r++) dst[r] = o[r];
    }
}

// ---------------- top-K per row: rank-select threshold + bitonic sort ----------------
// (identical to the validated R10/R12 version)
__global__ __launch_bounds__(256, 8) void topk_kernel(const f32x4* __restrict__ Ca4,
                                                      const float* __restrict__ mask,
                                                      int* __restrict__ eidx_ws,
                                                      float* __restrict__ dnb_ws,
                                                      float* __restrict__ out_eidx_f) {
    __shared__ unsigned long long cand[512];
    __shared__ int wint[2][4];
    __shared__ int gcnt[4];  // DEDICATED gather totals (reusing wint[0] races — R4/R5 bug)
    __shared__ float wflt[4];
    int row = blockIdx.x;
    int b = row >> 12;
    int tid = threadIdx.x;
    int w = tid >> 6, lane = tid & 63;
    float3 ci = loadCa4(Ca4, b, row & (LL - 1));
    float mi = mask[row];
    float dreg[16];
    unsigned mfl = 0;
    float localmax = 0.f;
#pragma unroll
    for (int s = 0; s < 16; s++) {
        int j = tid + s * 256;
        f32x4 pj = Ca4[b * LL + j];
        float dx = pj[0] - ci.x, dy = pj[1] - ci.y, dz = pj[2] - ci.z;
        float d = sqrtf(dx * dx + dy * dy + dz * dz + 1e-6f);
        float m2 = mi * mask[b * LL + j];
        float D = m2 * d;
        dreg[s] = D;
        mfl |= (m2 == 0.f ? 1u : 0u) << s;
        localmax = fmaxf(localmax, D);
    }
#pragma unroll
    for (int o = 32; o; o >>= 1) localmax = fmaxf(localmax, __shfl_xor(localmax, o));
    if (lane == 0) wflt[w] = localmax;
    __syncthreads();
    float dmax = fmaxf(fmaxf(wflt[0], wflt[1]), fmaxf(wflt[2], wflt[3]));
    unsigned ui[16];
#pragma unroll
    for (int s = 0; s < 16; s++)
        ui[s] = __float_as_uint(dreg[s] + (((mfl >> s) & 1) ? dmax : 0.f));
    unsigned lo = 0u, hi = 0x7f800000u, T = 0u;
    bool found = false;
    int p = 0;
    for (int it = 0; it < 24 && !found; ++it) {
        unsigned mid = (lo + hi) >> 1;
        int c = 0;
#pragma unroll
        for (int s = 0; s < 16; s++) c += (ui[s] < mid) ? 1 : 0;
#pragma unroll
        for (int o = 32; o; o >>= 1) c += __shfl_xor(c, o);
        if (lane == 0) wint[p][w] = c;
        __syncthreads();
        c = wint[p][0] + wint[p][1] + wint[p][2] + wint[p][3];
        p ^= 1;
        if (c < 30) lo = mid;
        else if (c > 64) hi = mid;
        else { T = mid; found = true; }
    }
    if (!found) T = hi;
    int cnt = 0;
#pragma unroll
    for (int s = 0; s < 16; s++) cnt += (ui[s] < T) ? 1 : 0;
    int inc = cnt;
#pragma unroll
    for (int o = 1; o < 64; o <<= 1) {
        int nv = __shfl_up(inc, o);
        if (lane >= o) inc += nv;
    }
    if (lane == 63) gcnt[w] = inc;
    __syncthreads();
    int C = gcnt[0] + gcnt[1] + gcnt[2] + gcnt[3];
    int waveoff = 0;
    for (int q = 0; q < 4; q++) waveoff += (q < w) ? gcnt[q] : 0;
    int slot = waveoff + inc - cnt;
#pragma unroll
    for (int s = 0; s < 16; s++) {
        if (ui[s] < T) {
            int j = tid + s * 256;
            if (slot < 512)
                cand[slot] = ((unsigned long long)ui[s] << 32) | (unsigned)j;
            slot++;
        }
    }
    __syncthreads();
    if (w != 0) return;
    if (C <= 64) {
        unsigned long long v = (lane < C) ? cand[lane] : ~0ull;
#pragma unroll
        for (int k = 2; k <= 64; k <<= 1) {
#pragma unroll
            for (int jj = k >> 1; jj > 0; jj >>= 1) {
                unsigned long long o = __shfl_xor(v, jj);
                bool take_min = (((lane & jj) == 0) == ((lane & k) == 0));
                bool lt = (o < v);
                v = (take_min == lt) ? o : v;
            }
        }
        if (lane < KK) {
            int j = (int)(v & 0xffffffffu);
            eidx_ws[row * KK + lane] = j;
            dnb_ws[row * KK + lane] = __uint_as_float((unsigned)(v >> 32));
            out_eidx_f[row * KK + lane] = (float)j;
        }
    } else {
        unsigned long long r[8];
#pragma unroll
        for (int q = 0; q < 8; q++) {
            int idx = lane + 64 * q;
            r[q] = (idx < C && idx < 512) ? cand[idx] : ~0ull;
        }
        for (int t = 0; t < KK; t++) {
            unsigned long long v = r[0];
#pragma unroll
            for (int q = 1; q < 8; q++) v = (r[q] < v) ? r[q] : v;
#pragma unroll
            for (int o = 32; o; o >>= 1) {
                unsigned long long u = __shfl_xor(v, o);
                if (u < v) v = u;
            }
            if (lane == 0) {
                int j = (int)(v & 0xffffffffu);
                eidx_ws[row * KK + t] = j;
                dnb_ws[row * KK + t] = __uint_as_float((unsigned)(v >> 32));
                out_eidx_f[row * KK + t] = (float)j;
            }
#pragma unroll
            for (int q = 0; q < 8; q++)
                if (r[q] == v) r[q] = ~0ull;
        }
    }
}

// -------- edge: 1 row / 128-thread block, M=32 tile, col-split MFMA + LN --------
__global__ __launch_bounds__(128) void edge_kernel(const f32x4* __restrict__ Ca4,
                                                   const int* __restrict__ ridx,
                                                   const int* __restrict__ chl,
                                                   const half_t* __restrict__ pwt,
                                                   const half_t* __restrict__ Bp,
                                                   const float* __restrict__ ln_g,
                                                   const float* __restrict__ ln_b,
                                                   const float* __restrict__ Of,
                                                   const int* __restrict__ eidx_ws,
                                                   const float* __restrict__ dnb_ws,
                                                   float* __restrict__ outE) {
    __shared__ alignas(16) half_t featH[32][FROW];  // 12800 B
    __shared__ float sD[30][10];                    // 1200 B
    __shared__ float psum[32][2], pssq[32][2];      // 512 B
    __shared__ float rmu[32], rinv[32];             // 256 B  -> ~14.8 KB total
    int grow = blockIdx.x;  // one (b, i) row per block
    int b = grow >> 12;
    int i = grow & (LL - 1);
    int tid = threadIdx.x;

    // P0: threads 0..59 = 2 threads/edge (load points once); threads 64..113 zero
    // pad rows 30,31 (MUST be zeroed every launch — replay-garbage rule).
    if (tid < 60) {
        int e = tid >> 1, half = tid & 1;
        int j = eidx_ws[grow * KK + e];
        if (half == 0) {
            float3 Pi0 = shiftedCa4(Ca4, b, i, 0);
            float3 Pi2 = shiftedCa4(Ca4, b, i, 2);
            float3 Pj0 = shiftedCa4(Ca4, b, j, 0);
            float3 Pj1 = loadCa4(Ca4, b, j);
            float3 Pj2 = shiftedCa4(Ca4, b, j, 2);
            sD[e][0] = dnb_ws[grow * KK + e];
            sD[e][1] = pdist(Pi0, Pj0);
            sD[e][2] = pdist(Pi2, Pj2);
            sD[e][3] = pdist(Pi0, Pj1);
            sD[e][4] = pdist(Pi0, Pj2);
            int off = ridx[grow] - ridx[b * LL + j];
            int eqc = (chl[grow] == chl[b * LL + j]) ? 1 : 0;
            int d = off + 32;
            d = d < 0 ? 0 : (d > 64 ? 64 : d);
            d = eqc ? d : 65;
            *(half8*)&featH[e][0] = *(const half8*)(pwt + d * 16);
            *(half8*)&featH[e][8] = *(const half8*)(pwt + d * 16 + 8);
        } else {
            float3 Pi1 = loadCa4(Ca4, b, i);
            float3 Pi2 = shiftedCa4(Ca4, b, i, 2);
            float3 Pj0 = shiftedCa4(Ca4, b, j, 0);
            float3 Pj1 = loadCa4(Ca4, b, j);
            float3 Pj2 = shiftedCa4(Ca4, b, j, 2);
            sD[e][5] = pdist(Pi1, Pj0);
            sD[e][6] = pdist(Pi1, Pj2);
            sD[e][7] = pdist(Pi2, Pj0);
            sD[e][8] = pdist(Pi2, Pj1);
            float Oi[9], Oj[9];
#pragma unroll
            for (int r = 0; r < 9; r++) {
                Oi[r] = Of[(size_t)grow * 9 + r];
                Oj[r] = Of[((size_t)(b * LL + j)) * 9 + r];
            }
            float dx = Pj1.x - Pi1.x, dy = Pj1.y - Pi1.y, dz = Pj1.z - Pi1.z;
            float v0 = Oi[0] * dx + Oi[1] * dy + Oi[2] * dz;
            float v1 = Oi[3] * dx + Oi[4] * dy + Oi[5] * dz;
            float v2 = Oi[6] * dx + Oi[7] * dy + Oi[8] * dz;
            float nn = sqrtf(v0 * v0 + v1 * v1 + v2 * v2);
            float ninv = 1.f / fmaxf(nn, 1e-12f);
            float R[3][3];
#pragma unroll
            for (int m = 0; m < 3; m++)
#pragma unroll
                for (int n = 0; n < 3; n++)
                    R[m][n] = Oi[0 * 3 + m] * Oj[0 * 3 + n] + Oi[1 * 3 + m] * Oj[1 * 3 + n] +
                              Oi[2 * 3 + m] * Oj[2 * 3 + n];
            float Rxx = R[0][0], Ryy = R[1][1], Rzz = R[2][2];
            float m0 = 0.5f * sqrtf(fabsf(1.f + Rxx - Ryy - Rzz));
            float m1 = 0.5f * sqrtf(fabsf(1.f - Rxx + Ryy - Rzz));
            float m2 = 0.5f * sqrtf(fabsf(1.f - Rxx - Ryy + Rzz));
            float x = sgnf(R[2][1] - R[1][2]) * m0;
            float y = sgnf(R[0][2] - R[2][0]) * m1;
            float z = sgnf(R[1][0] - R[0][1]) * m2;
            float ww = 0.5f * sqrtf(fmaxf(1.f + Rxx + Ryy + Rzz, 0.f));
            float qn = sqrtf(x * x + y * y + z * z + ww * ww);
            float qi = 1.f / fmaxf(qn, 1e-12f);
            half8 h;
            h[0] = (half_t)(v0 * ninv);
            h[1] = (half_t)(v1 * ninv);
            h[2] = (half_t)(v2 * ninv);
            h[3] = (half_t)(x * qi);
            h[4] = (half_t)(y * qi);
            h[5] = (half_t)(z * qi);
            h[6] = (half_t)(ww * qi);
            h[7] = (half_t)0.f;
            half8 zv = {};
            *(half8*)&featH[e][160] = h;   // cols 160..167 (167 = 0)
            *(half8*)&featH[e][168] = zv;  // zero k-pad; MFMA reads up to col 192
            *(half8*)&featH[e][176] = zv;
            *(half8*)&featH[e][184] = zv;
        }
    } else if (tid >= 64 && tid < 114) {
        int t = tid - 64;  // 0..49: zero rows 30,31 (25 half8 chunks each)
        int r = 30 + t / 25, c = t % 25;
        half8 zv = {};
        *(half8*)&featH[r][c * 8] = zv;
    }
    __syncthreads();

    // P1: 270 uniform RBF jobs (edge x group), LDS-only inputs
    for (int job = tid; job < 270; job += 128) {
        int e = job / 9, q = job - e * 9;
        float D = sD[e][q];
        half8 v0, v1;
#pragma unroll
        for (int m = 0; m < 8; m++) {
            float mu = 2.0f + (4.f / 3.f) * (float)m;
            float t = (D - mu) * 0.8f;
            v0[m] = (half_t)exp2f(t * t * -1.4426950408889634f);
        }
#pragma unroll
        for (int m = 8; m < 16; m++) {
            float mu = 2.0f + (4.f / 3.f) * (float)m;
            float t = (D - mu) * 0.8f;
            v1[m - 8] = (half_t)exp2f(t * t * -1.4426950408889634f);
        }
        *(half8*)&featH[e][16 + 16 * q] = v0;
        *(half8*)&featH[e][24 + 16 * q] = v1;
    }
    __syncthreads();

    // P2: col-split MFMA — wave w (of 2) owns 32 rows x cols [64w, 64w+64)
    int lane = tid & 63, w = tid >> 6;
    int cc = lane & 15, g = lane >> 4;
    f32x4 zero = {0.f, 0.f, 0.f, 0.f};
    f32x4 acc[2][4];
#pragma unroll
    for (int m = 0; m < 2; m++)
#pragma unroll
        for (int t = 0; t < 4; t++) acc[m][t] = zero;
    for (int s = 0; s < 6; s++) {
        int ko = 32 * s + 8 * g;
        half8 af0 = *(const half8*)&featH[cc][ko];
        half8 af1 = *(const half8*)&featH[16 + cc][ko];
#pragma unroll
        for (int t = 0; t < 4; t++) {
            half8 bf = *(const half8*)(Bp + ((size_t)(((4 * w + t) * 6 + s) * 64 + lane)) * 8);
            acc[0][t] = __builtin_amdgcn_mfma_f32_16x16x32_f16(af0, bf, acc[0][t], 0, 0, 0);
            acc[1][t] = __builtin_amdgcn_mfma_f32_16x16x32_f16(af1, bf, acc[1][t], 0, 0, 0);
        }
    }

    // P3: per-row LN partials within the wave's 64-col slice -> psum/pssq[row][w]
#pragma unroll
    for (int m = 0; m < 2; m++) {
#pragma unroll
        for (int q = 0; q < 4; q++) {
            float sp = acc[m][0][q] + acc[m][1][q] + acc[m][2][q] + acc[m][3][q];
            float qp = acc[m][0][q] * acc[m][0][q] + acc[m][1][q] * acc[m][1][q] +
                       acc[m][2][q] * acc[m][2][q] + acc[m][3][q] * acc[m][3][q];
#pragma unroll
            for (int o = 1; o < 16; o <<= 1) {
                sp += __shfl_xor(sp, o);
                qp += __shfl_xor(qp, o);
            }
            if (cc == 0) {
                int r = 16 * m + 4 * g + q;
                psum[r][w] = sp;
                pssq[r][w] = qp;
            }
        }
    }
    __syncthreads();
    if (tid < 32) {
        float sum = psum[tid][0] + psum[tid][1];
        float ssq = pssq[tid][0] + pssq[tid][1];
        float mu = sum * (1.f / 128.f);
        float var = fmaxf(ssq * (1.f / 128.f) - mu * mu, 0.f);
        rmu[tid] = mu;
        rinv[tid] = 1.f / sqrtf(var + 1e-5f);
    }
    __syncthreads();

    // P4: normalize + store directly from registers
    float lgv[4], lbv[4];
#pragma unroll
    for (int t = 0; t < 4; t++) {
        lgv[t] = ln_g[64 * w + 16 * t + cc];
        lbv[t] = ln_b[64 * w + 16 * t + cc];
    }
#pragma unroll
    for (int m = 0; m < 2; m++) {
#pragma unroll
        for (int q = 0; q < 4; q++) {
            int r = 16 * m + 4 * g + q;
            if (r < KK) {
                float mu = rmu[r], invs = rinv[r];
                float* dst = outE + ((size_t)(grow * KK + r)) * CDIM + 64 * w + cc;
#pragma unroll
                for (int t = 0; t < 4; t++)
                    dst[16 * t] = (acc[m][t][q] - mu) * invs * lgv[t] + lbv[t];
            }
        }
    }
}

extern "C" void kernel_launch(void* const* d_in, const int* in_sizes, int n_in,
                              void* d_out, int out_size, void* d_ws, size_t ws_size,
                              hipStream_t stream) {
    const float* Ca = (const float*)d_in[0];
    const float* mask = (const float*)d_in[1];
    const int* ridx = (const int*)d_in[2];
    const int* chl = (const int*)d_in[3];
    const float* posW = (const float*)d_in[4];
    const float* posb = (const float*)d_in[5];
    const float* edgeW = (const float*)d_in[6];
    const float* lng = (const float*)d_in[7];
    const float* lnb = (const float*)d_in[8];

    float* outE = (float*)d_out;
    float* outEidxF = outE + (size_t)NB * LL * KK * CDIM;

    char* ws = (char*)d_ws;
    half_t* Bp = (half_t*)ws;                     // 49152 B
    half_t* pwt = (half_t*)(ws + 49152);          // 2112 B
    float* Of = (float*)(ws + 51264);             // 294912 B
    int* eidx = (int*)(ws + 346176);              // 983040 B
    float* dnb = (float*)(ws + 1329216);          // 983040 B
    f32x4* Ca4 = (f32x4*)(ws + 2312256);          // 131072 B

    prep_kernel<<<17 + (NB * LL + 255) / 256, 256, 0, stream>>>(edgeW, posW, posb, Ca,
                                                                Bp, pwt, Of, Ca4);
    topk_kernel<<<NB * LL, 256, 0, stream>>>(Ca4, mask, eidx, dnb, outEidxF);
    edge_kernel<<<NB * LL, 128, 0, stream>>>(Ca4, ridx, chl, pwt, Bp, lng, lnb,
                                             Of, eidx, dnb, outE);
}

// Round 14
// 114.943 us; speedup vs baseline: 1.2672x; 1.0073x over previous
//
#include <hip/hip_runtime.h>
#include <stdint.h>

#define LL 4096
#define NB 2
#define KK 30
#define CDIM 128
#define FROW 200  // feat row stride in halves (400 B, multiple of 16 B)

typedef _Float16 half_t;
typedef half_t half8 __attribute__((ext_vector_type(8)));
typedef float f32x4 __attribute__((ext_vector_type(4)));

__device__ __forceinline__ float3 loadCa(const float* __restrict__ Ca, int b, int idx) {
    const float* p = Ca + ((size_t)(b * LL + idx)) * 3;
    return make_float3(p[0], p[1], p[2]);
}
__device__ __forceinline__ float3 loadCa4(const f32x4* __restrict__ Ca4, int b, int idx) {
    f32x4 v = Ca4[b * LL + idx];
    return make_float3(v[0], v[1], v[2]);
}
__device__ __forceinline__ float3 shiftedCa4(const f32x4* __restrict__ Ca4, int b, int idx, int sel) {
    int jj = idx + sel - 1;
    if (jj < 0 || jj >= LL) return make_float3(0.f, 0.f, 0.f);
    return loadCa4(Ca4, b, jj);
}
__device__ __forceinline__ float sgnf(float x) { return (x > 0.f) ? 1.f : ((x < 0.f) ? -1.f : 0.f); }
__device__ __forceinline__ float pdist(float3 a, float3 c) {
    float dx = a.x - c.x, dy = a.y - c.y, dz = a.z - c.z;
    return sqrtf(dx * dx + dy * dy + dz * dz + 1e-6f);
}

// ------- prep: W pack (f16 B-frags) + posW transpose + local frames + Ca float4 copy -------
__global__ __launch_bounds__(256) void prep_kernel(const float* __restrict__ W,
                                                   const float* __restrict__ posW,
                                                   const float* __restrict__ posb,
                                                   const float* __restrict__ Ca,
                                                   half_t* __restrict__ Bp,
                                                   half_t* __restrict__ pwt,
                                                   float* __restrict__ Of,
                                                   f32x4* __restrict__ Ca4) {
    int blk = blockIdx.x;
    int tid = threadIdx.x;
    if (blk < 12) {
        // Bp[((T*6+s)*64 + l)*8 + e] = W[n=16T+(l&15)][k=32s+8*(l>>4)+e], 0 if k>=167
        int idx = blk * 256 + tid;
        if (idx >= 8 * 6 * 64) return;
        int l = idx & 63;
        int ts = idx >> 6;
        int s = ts % 6, t = ts / 6;
        int n = 16 * t + (l & 15);
        int kbase = 32 * s + 8 * (l >> 4);
        half8 v;
#pragma unroll
        for (int e = 0; e < 8; e++) {
            int k = kbase + e;
            v[e] = (k < 167) ? (half_t)W[n * 167 + k] : (half_t)0.f;
        }
        *(half8*)(Bp + (size_t)idx * 8) = v;
    } else if (blk < 17) {
        int idx = (blk - 12) * 256 + tid;
        if (idx < 66 * 16) {
            int d = idx >> 4, p = idx & 15;
            pwt[d * 16 + p] = (half_t)(posW[p * 66 + d] + posb[p]);
        }
    } else {
        int t = (blk - 17) * 256 + tid;
        if (t >= NB * LL) return;
        int b = t >> 12, i = t & (LL - 1);
        f32x4 c4;
        c4[0] = Ca[(size_t)t * 3];
        c4[1] = Ca[(size_t)t * 3 + 1];
        c4[2] = Ca[(size_t)t * 3 + 2];
        c4[3] = 0.f;
        Ca4[t] = c4;
        float o[9] = {0.f, 0.f, 0.f, 0.f, 0.f, 0.f, 0.f, 0.f, 0.f};
        if (i >= 1 && i <= LL - 3) {
            float3 cm = loadCa(Ca, b, i - 1), cc = loadCa(Ca, b, i), cp = loadCa(Ca, b, i + 1);
            float dx0 = cc.x - cm.x, dy0 = cc.y - cm.y, dz0 = cc.z - cm.z;
            float n0 = sqrtf(dx0 * dx0 + dy0 * dy0 + dz0 * dz0);
            float k0 = (n0 > 3.6f && n0 < 4.0f) ? 1.f : 0.f;
            float s0 = k0 / fmaxf(n0 * k0, 1e-12f);
            float u2x = dx0 * s0, u2y = dy0 * s0, u2z = dz0 * s0;
            float dx1 = cp.x - cc.x, dy1 = cp.y - cc.y, dz1 = cp.z - cc.z;
            float n1 = sqrtf(dx1 * dx1 + dy1 * dy1 + dz1 * dz1);
            float k1 = (n1 > 3.6f && n1 < 4.0f) ? 1.f : 0.f;
            float s1 = k1 / fmaxf(n1 * k1, 1e-12f);
            float u1x = dx1 * s1, u1y = dy1 * s1, u1z = dz1 * s1;
            float cx = u2y * u1z - u2z * u1y;
            float cy = u2z * u1x - u2x * u1z;
            float cz = u2x * u1y - u2y * u1x;
            float cn = sqrtf(cx * cx + cy * cy + cz * cz);
            float cinv = 1.f / fmaxf(cn, 1e-12f);
            float n2x = cx * cinv, n2y = cy * cinv, n2z = cz * cinv;
            float ox = u2x - u1x, oy = u2y - u1y, oz = u2z - u1z;
            float on = sqrtf(ox * ox + oy * oy + oz * oz);
            float oinv = 1.f / fmaxf(on, 1e-12f);
            float o1x = ox * oinv, o1y = oy * oinv, o1z = oz * oinv;
            o[0] = o1x; o[1] = o1y; o[2] = o1z;
            o[3] = n2x; o[4] = n2y; o[5] = n2z;
            o[6] = o1y * n2z - o1z * n2y;
            o[7] = o1z * n2x - o1x * n2z;
            o[8] = o1x * n2y - o1y * n2x;
        }
        float* dst = Of + (size_t)t * 9;
#pragma unroll
        for (int r = 0; r < 9; r++) dst[r] = o[r];
    }
}

// ---- fused: topk (R12-proven) -> features -> MFMA 32x128x192 -> LN, one row/block ----
__global__ __launch_bounds__(256) void fused_kernel(const f32x4* __restrict__ Ca4,
                                                    const float* __restrict__ mask,
                                                    const int* __restrict__ ridx,
                                                    const int* __restrict__ chl,
                                                    const half_t* __restrict__ pwt,
                                                    const half_t* __restrict__ Bp,
                                                    const float* __restrict__ ln_g,
                                                    const float* __restrict__ ln_b,
                                                    const float* __restrict__ Of,
                                                    float* __restrict__ outE,
                                                    float* __restrict__ out_eidx_f) {
    // cand (topk phase) and featH (feature/MFMA phases) are barrier-separated -> union
    __shared__ alignas(16) char smem[32 * FROW * 2];  // 12800 B
    unsigned long long* cand = (unsigned long long*)smem;       // 512 u64 = 4096 B
    half_t(*featH)[FROW] = (half_t(*)[FROW])smem;               // 32 x 200 halves
    __shared__ int wint[2][4];
    __shared__ int gcnt[4];  // DEDICATED gather totals (reusing wint[0] races — R4/R5 bug)
    __shared__ float wflt[4];
    __shared__ int sj[32];     // top-30 neighbor index handoff (LDS, not global)
    __shared__ float sd0[32];  // top-30 distance handoff
    __shared__ float sD[30][10];
    __shared__ float psum[32][4], pssq[32][4];
    __shared__ float rmu[32], rinv[32];

    int row = blockIdx.x;
    int b = row >> 12;
    int i = row & (LL - 1);
    int tid = threadIdx.x;
    int w = tid >> 6, lane = tid & 63;

    // ================= Phase T: top-30 (identical search to R12) =================
    float3 ci = loadCa4(Ca4, b, i);
    float mi = mask[row];
    float dreg[16];
    unsigned mfl = 0;
    float localmax = 0.f;
#pragma unroll
    for (int s = 0; s < 16; s++) {
        int j = tid + s * 256;
        f32x4 pj = Ca4[b * LL + j];
        float dx = pj[0] - ci.x, dy = pj[1] - ci.y, dz = pj[2] - ci.z;
        float d = sqrtf(dx * dx + dy * dy + dz * dz + 1e-6f);
        float m2 = mi * mask[b * LL + j];
        float D = m2 * d;
        dreg[s] = D;
        mfl |= (m2 == 0.f ? 1u : 0u) << s;
        localmax = fmaxf(localmax, D);
    }
#pragma unroll
    for (int o = 32; o; o >>= 1) localmax = fmaxf(localmax, __shfl_xor(localmax, o));
    if (lane == 0) wflt[w] = localmax;
    __syncthreads();
    float dmax = fmaxf(fmaxf(wflt[0], wflt[1]), fmaxf(wflt[2], wflt[3]));
    unsigned ui[16];
#pragma unroll
    for (int s = 0; s < 16; s++)
        ui[s] = __float_as_uint(dreg[s] + (((mfl >> s) & 1) ? dmax : 0.f));
    unsigned lo = 0u, hi = 0x7f800000u, T = 0u;
    bool found = false;
    int p = 0;
    for (int it = 0; it < 24 && !found; ++it) {
        unsigned mid = (lo + hi) >> 1;
        int c = 0;
#pragma unroll
        for (int s = 0; s < 16; s++) c += (ui[s] < mid) ? 1 : 0;
#pragma unroll
        for (int o = 32; o; o >>= 1) c += __shfl_xor(c, o);
        if (lane == 0) wint[p][w] = c;
        __syncthreads();
        c = wint[p][0] + wint[p][1] + wint[p][2] + wint[p][3];
        p ^= 1;
        if (c < 30) lo = mid;
        else if (c > 64) hi = mid;
        else { T = mid; found = true; }
    }
    if (!found) T = hi;
    int cnt = 0;
#pragma unroll
    for (int s = 0; s < 16; s++) cnt += (ui[s] < T) ? 1 : 0;
    int inc = cnt;
#pragma unroll
    for (int o = 1; o < 64; o <<= 1) {
        int nv = __shfl_up(inc, o);
        if (lane >= o) inc += nv;
    }
    if (lane == 63) gcnt[w] = inc;
    __syncthreads();
    int C = gcnt[0] + gcnt[1] + gcnt[2] + gcnt[3];
    int waveoff = 0;
    for (int q = 0; q < 4; q++) waveoff += (q < w) ? gcnt[q] : 0;
    int slot = waveoff + inc - cnt;
#pragma unroll
    for (int s = 0; s < 16; s++) {
        if (ui[s] < T) {
            int j = tid + s * 256;
            if (slot < 512)
                cand[slot] = ((unsigned long long)ui[s] << 32) | (unsigned)j;
            slot++;
        }
    }
    __syncthreads();
    if (w == 0) {
        if (C <= 64) {
            unsigned long long v = (lane < C) ? cand[lane] : ~0ull;
#pragma unroll
            for (int k = 2; k <= 64; k <<= 1) {
#pragma unroll
                for (int jj = k >> 1; jj > 0; jj >>= 1) {
                    unsigned long long o = __shfl_xor(v, jj);
                    bool take_min = (((lane & jj) == 0) == ((lane & k) == 0));
                    bool lt = (o < v);
                    v = (take_min == lt) ? o : v;
                }
            }
            if (lane < KK) {
                int j = (int)(v & 0xffffffffu);
                sj[lane] = j;
                sd0[lane] = __uint_as_float((unsigned)(v >> 32));
                out_eidx_f[row * KK + lane] = (float)j;
            }
        } else {
            unsigned long long r[8];
#pragma unroll
            for (int q = 0; q < 8; q++) {
                int idx = lane + 64 * q;
                r[q] = (idx < C && idx < 512) ? cand[idx] : ~0ull;
            }
            for (int t = 0; t < KK; t++) {
                unsigned long long v = r[0];
#pragma unroll
                for (int q = 1; q < 8; q++) v = (r[q] < v) ? r[q] : v;
#pragma unroll
                for (int o = 32; o; o >>= 1) {
                    unsigned long long u = __shfl_xor(v, o);
                    if (u < v) v = u;
                }
                if (lane == 0) {
                    int j = (int)(v & 0xffffffffu);
                    sj[t] = j;
                    sd0[t] = __uint_as_float((unsigned)(v >> 32));
                    out_eidx_f[row * KK + t] = (float)j;
                }
#pragma unroll
                for (int q = 0; q < 8; q++)
                    if (r[q] == v) r[q] = ~0ull;
            }
        }
    }
    __syncthreads();  // cand dead beyond this point; featH (same bytes) may be written

    // ================= Phase P0: per-edge gather (2 threads/edge) =================
    if (tid < 60) {
        int e = tid >> 1, half = tid & 1;
        int j = sj[e];
        if (half == 0) {
            float3 Pi0 = shiftedCa4(Ca4, b, i, 0);
            float3 Pi2 = shiftedCa4(Ca4, b, i, 2);
            float3 Pj0 = shiftedCa4(Ca4, b, j, 0);
            float3 Pj1 = loadCa4(Ca4, b, j);
            float3 Pj2 = shiftedCa4(Ca4, b, j, 2);
            sD[e][0] = sd0[e];
            sD[e][1] = pdist(Pi0, Pj0);
            sD[e][2] = pdist(Pi2, Pj2);
            sD[e][3] = pdist(Pi0, Pj1);
            sD[e][4] = pdist(Pi0, Pj2);
            int off = ridx[row] - ridx[b * LL + j];
            int eqc = (chl[row] == chl[b * LL + j]) ? 1 : 0;
            int d = off + 32;
            d = d < 0 ? 0 : (d > 64 ? 64 : d);
            d = eqc ? d : 65;
            *(half8*)&featH[e][0] = *(const half8*)(pwt + d * 16);
            *(half8*)&featH[e][8] = *(const half8*)(pwt + d * 16 + 8);
        } else {
            float3 Pi1 = loadCa4(Ca4, b, i);
            float3 Pi2 = shiftedCa4(Ca4, b, i, 2);
            float3 Pj0 = shiftedCa4(Ca4, b, j, 0);
            float3 Pj1 = loadCa4(Ca4, b, j);
            float3 Pj2 = shiftedCa4(Ca4, b, j, 2);
            sD[e][5] = pdist(Pi1, Pj0);
            sD[e][6] = pdist(Pi1, Pj2);
            sD[e][7] = pdist(Pi2, Pj0);
            sD[e][8] = pdist(Pi2, Pj1);
            float Oi[9], Oj[9];
#pragma unroll
            for (int r = 0; r < 9; r++) {
                Oi[r] = Of[(size_t)row * 9 + r];
                Oj[r] = Of[((size_t)(b * LL + j)) * 9 + r];
            }
            float dx = Pj1.x - Pi1.x, dy = Pj1.y - Pi1.y, dz = Pj1.z - Pi1.z;
            float v0 = Oi[0] * dx + Oi[1] * dy + Oi[2] * dz;
            float v1 = Oi[3] * dx + Oi[4] * dy + Oi[5] * dz;
            float v2 = Oi[6] * dx + Oi[7] * dy + Oi[8] * dz;
            float nn = sqrtf(v0 * v0 + v1 * v1 + v2 * v2);
            float ninv = 1.f / fmaxf(nn, 1e-12f);
            float R[3][3];
#pragma unroll
            for (int m = 0; m < 3; m++)
#pragma unroll
                for (int n = 0; n < 3; n++)
                    R[m][n] = Oi[0 * 3 + m] * Oj[0 * 3 + n] + Oi[1 * 3 + m] * Oj[1 * 3 + n] +
                              Oi[2 * 3 + m] * Oj[2 * 3 + n];
            float Rxx = R[0][0], Ryy = R[1][1], Rzz = R[2][2];
            float m0 = 0.5f * sqrtf(fabsf(1.f + Rxx - Ryy - Rzz));
            float m1 = 0.5f * sqrtf(fabsf(1.f - Rxx + Ryy - Rzz));
            float m2 = 0.5f * sqrtf(fabsf(1.f - Rxx - Ryy + Rzz));
            float x = sgnf(R[2][1] - R[1][2]) * m0;
            float y = sgnf(R[0][2] - R[2][0]) * m1;
            float z = sgnf(R[1][0] - R[0][1]) * m2;
            float ww = 0.5f * sqrtf(fmaxf(1.f + Rxx + Ryy + Rzz, 0.f));
            float qn = sqrtf(x * x + y * y + z * z + ww * ww);
            float qi = 1.f / fmaxf(qn, 1e-12f);
            half8 h;
            h[0] = (half_t)(v0 * ninv);
            h[1] = (half_t)(v1 * ninv);
            h[2] = (half_t)(v2 * ninv);
            h[3] = (half_t)(x * qi);
            h[4] = (half_t)(y * qi);
            h[5] = (half_t)(z * qi);
            h[6] = (half_t)(ww * qi);
            h[7] = (half_t)0.f;
            half8 zv = {};
            *(half8*)&featH[e][160] = h;   // cols 160..167 (167 = 0)
            *(half8*)&featH[e][168] = zv;  // zero k-pad; MFMA reads up to col 192
            *(half8*)&featH[e][176] = zv;
            *(half8*)&featH[e][184] = zv;
        }
    } else if (tid >= 64 && tid < 114) {
        int t = tid - 64;  // 0..49: zero rows 30,31 (25 half8 chunks each)
        int r = 30 + t / 25, c = t % 25;
        half8 zv = {};
        *(half8*)&featH[r][c * 8] = zv;
    }
    __syncthreads();

    // ================= Phase P1: 270 uniform RBF jobs =================
    for (int job = tid; job < 270; job += 256) {
        int e = job / 9, q = job - e * 9;
        float D = sD[e][q];
        half8 v0, v1;
#pragma unroll
        for (int m = 0; m < 8; m++) {
            float mu = 2.0f + (4.f / 3.f) * (float)m;
            float t = (D - mu) * 0.8f;
            v0[m] = (half_t)exp2f(t * t * -1.4426950408889634f);
        }
#pragma unroll
        for (int m = 8; m < 16; m++) {
            float mu = 2.0f + (4.f / 3.f) * (float)m;
            float t = (D - mu) * 0.8f;
            v1[m - 8] = (half_t)exp2f(t * t * -1.4426950408889634f);
        }
        *(half8*)&featH[e][16 + 16 * q] = v0;
        *(half8*)&featH[e][24 + 16 * q] = v1;
    }
    __syncthreads();

    // ========== Phase P2: col-split MFMA — wave w owns 32 rows x cols [32w, 32w+32) ==========
    int cc = lane & 15, g = lane >> 4;
    f32x4 zero = {0.f, 0.f, 0.f, 0.f};
    f32x4 acc[2][2];
#pragma unroll
    for (int m = 0; m < 2; m++)
#pragma unroll
        for (int t = 0; t < 2; t++) acc[m][t] = zero;
    const half_t* b0p = Bp + ((size_t)(2 * w) * 6) * 64 * 8;
    const half_t* b1p = Bp + ((size_t)(2 * w + 1) * 6) * 64 * 8;
    for (int s = 0; s < 6; s++) {
        int ko = 32 * s + 8 * g;
        half8 af0 = *(const half8*)&featH[cc][ko];
        half8 af1 = *(const half8*)&featH[16 + cc][ko];
        half8 bf0 = *(const half8*)(b0p + (size_t)(s * 64 + lane) * 8);
        half8 bf1 = *(const half8*)(b1p + (size_t)(s * 64 + lane) * 8);
        acc[0][0] = __builtin_amdgcn_mfma_f32_16x16x32_f16(af0, bf0, acc[0][0], 0, 0, 0);
        acc[0][1] = __builtin_amdgcn_mfma_f32_16x16x32_f16(af0, bf1, acc[0][1], 0, 0, 0);
        acc[1][0] = __builtin_amdgcn_mfma_f32_16x16x32_f16(af1, bf0, acc[1][0], 0, 0, 0);
        acc[1][1] = __builtin_amdgcn_mfma_f32_16x16x32_f16(af1, bf1, acc[1][1], 0, 0, 0);
    }

    // ======= Phase P3: per-row LN partials within the wave's 32-col slice =======
#pragma unroll
    for (int m = 0; m < 2; m++) {
#pragma unroll
        for (int q = 0; q < 4; q++) {
            float v0 = acc[m][0][q], v1 = acc[m][1][q];
            float sp = v0 + v1;
            float qp = v0 * v0 + v1 * v1;
#pragma unroll
            for (int o = 1; o < 16; o <<= 1) {
                sp += __shfl_xor(sp, o);
                qp += __shfl_xor(qp, o);
            }
            if (cc == 0) {
                int r = 16 * m + 4 * g + q;
                psum[r][w] = sp;
                pssq[r][w] = qp;
            }
        }
    }
    __syncthreads();
    if (tid < 32) {
        float sum = psum[tid][0] + psum[tid][1] + psum[tid][2] + psum[tid][3];
        float ssq = pssq[tid][0] + pssq[tid][1] + pssq[tid][2] + pssq[tid][3];
        float mu = sum * (1.f / 128.f);
        float var = fmaxf(ssq * (1.f / 128.f) - mu * mu, 0.f);
        rmu[tid] = mu;
        rinv[tid] = 1.f / sqrtf(var + 1e-5f);
    }
    __syncthreads();

    // ================= Phase P4: normalize + store =================
    float lgv[2], lbv[2];
#pragma unroll
    for (int tt = 0; tt < 2; tt++) {
        lgv[tt] = ln_g[32 * w + 16 * tt + cc];
        lbv[tt] = ln_b[32 * w + 16 * tt + cc];
    }
#pragma unroll
    for (int m = 0; m < 2; m++) {
#pragma unroll
        for (int q = 0; q < 4; q++) {
            int r = 16 * m + 4 * g + q;
            if (r < KK) {
                float mu = rmu[r], invs = rinv[r];
                float* dst = outE + ((size_t)(row * KK + r)) * CDIM + 32 * w + cc;
                dst[0] = (acc[m][0][q] - mu) * invs * lgv[0] + lbv[0];
                dst[16] = (acc[m][1][q] - mu) * invs * lgv[1] + lbv[1];
            }
        }
    }
}

extern "C" void kernel_launch(void* const* d_in, const int* in_sizes, int n_in,
                              void* d_out, int out_size, void* d_ws, size_t ws_size,
                              hipStream_t stream) {
    const float* Ca = (const float*)d_in[0];
    const float* mask = (const float*)d_in[1];
    const int* ridx = (const int*)d_in[2];
    const int* chl = (const int*)d_in[3];
    const float* posW = (const float*)d_in[4];
    const float* posb = (const float*)d_in[5];
    const float* edgeW = (const float*)d_in[6];
    const float* lng = (const float*)d_in[7];
    const float* lnb = (const float*)d_in[8];

    float* outE = (float*)d_out;
    float* outEidxF = outE + (size_t)NB * LL * KK * CDIM;

    char* ws = (char*)d_ws;
    half_t* Bp = (half_t*)ws;                     // 49152 B
    half_t* pwt = (half_t*)(ws + 49152);          // 2112 B
    float* Of = (float*)(ws + 51264);             // 294912 B
    f32x4* Ca4 = (f32x4*)(ws + 346176);           // 131072 B

    prep_kernel<<<17 + (NB * LL + 255) / 256, 256, 0, stream>>>(edgeW, posW, posb, Ca,
                                                                Bp, pwt, Of, Ca4);
    fused_kernel<<<NB * LL, 256, 0, stream>>>(Ca4, mask, ridx, chl, pwt, Bp, lng, lnb,
                                              Of, outE, outEidxF);
}

// Round 15
// 104.890 us; speedup vs baseline: 1.3886x; 1.0958x over previous
//
#include <hip/hip_runtime.h>
#include <stdint.h>

#define LL 4096
#define NB 2
#define KK 30
#define CDIM 128
#define FROW 200  // feat row stride in halves (400 B, multiple of 16 B)

typedef _Float16 half_t;
typedef half_t half8 __attribute__((ext_vector_type(8)));
typedef float f32x4 __attribute__((ext_vector_type(4)));

__device__ __forceinline__ float3 loadCa(const float* __restrict__ Ca, int b, int idx) {
    const float* p = Ca + ((size_t)(b * LL + idx)) * 3;
    return make_float3(p[0], p[1], p[2]);
}
__device__ __forceinline__ float3 loadCa4(const f32x4* __restrict__ Ca4, int b, int idx) {
    f32x4 v = Ca4[b * LL + idx];
    return make_float3(v[0], v[1], v[2]);
}
__device__ __forceinline__ float3 shiftedCa4(const f32x4* __restrict__ Ca4, int b, int idx, int sel) {
    int jj = idx + sel - 1;
    if (jj < 0 || jj >= LL) return make_float3(0.f, 0.f, 0.f);
    return loadCa4(Ca4, b, jj);
}
__device__ __forceinline__ float sgnf(float x) { return (x > 0.f) ? 1.f : ((x < 0.f) ? -1.f : 0.f); }
__device__ __forceinline__ float pdist(float3 a, float3 c) {
    float dx = a.x - c.x, dy = a.y - c.y, dz = a.z - c.z;
    return sqrtf(dx * dx + dy * dy + dz * dz + 1e-6f);
}

// ------- prep: W pack (f16 B-frags) + posW transpose + local frames + Ca float4 copy -------
__global__ __launch_bounds__(256) void prep_kernel(const float* __restrict__ W,
                                                   const float* __restrict__ posW,
                                                   const float* __restrict__ posb,
                                                   const float* __restrict__ Ca,
                                                   half_t* __restrict__ Bp,
                                                   half_t* __restrict__ pwt,
                                                   float* __restrict__ Of,
                                                   f32x4* __restrict__ Ca4) {
    int blk = blockIdx.x;
    int tid = threadIdx.x;
    if (blk < 12) {
        // Bp[((T*6+s)*64 + l)*8 + e] = W[n=16T+(l&15)][k=32s+8*(l>>4)+e], 0 if k>=167
        int idx = blk * 256 + tid;
        if (idx >= 8 * 6 * 64) return;
        int l = idx & 63;
        int ts = idx >> 6;
        int s = ts % 6, t = ts / 6;
        int n = 16 * t + (l & 15);
        int kbase = 32 * s + 8 * (l >> 4);
        half8 v;
#pragma unroll
        for (int e = 0; e < 8; e++) {
            int k = kbase + e;
            v[e] = (k < 167) ? (half_t)W[n * 167 + k] : (half_t)0.f;
        }
        *(half8*)(Bp + (size_t)idx * 8) = v;
    } else if (blk < 17) {
        int idx = (blk - 12) * 256 + tid;
        if (idx < 66 * 16) {
            int d = idx >> 4, p = idx & 15;
            pwt[d * 16 + p] = (half_t)(posW[p * 66 + d] + posb[p]);
        }
    } else {
        int t = (blk - 17) * 256 + tid;
        if (t >= NB * LL) return;
        int b = t >> 12, i = t & (LL - 1);
        f32x4 c4;
        c4[0] = Ca[(size_t)t * 3];
        c4[1] = Ca[(size_t)t * 3 + 1];
        c4[2] = Ca[(size_t)t * 3 + 2];
        c4[3] = 0.f;
        Ca4[t] = c4;
        float o[9] = {0.f, 0.f, 0.f, 0.f, 0.f, 0.f, 0.f, 0.f, 0.f};
        if (i >= 1 && i <= LL - 3) {
            float3 cm = loadCa(Ca, b, i - 1), cc = loadCa(Ca, b, i), cp = loadCa(Ca, b, i + 1);
            float dx0 = cc.x - cm.x, dy0 = cc.y - cm.y, dz0 = cc.z - cm.z;
            float n0 = sqrtf(dx0 * dx0 + dy0 * dy0 + dz0 * dz0);
            float k0 = (n0 > 3.6f && n0 < 4.0f) ? 1.f : 0.f;
            float s0 = k0 / fmaxf(n0 * k0, 1e-12f);
            float u2x = dx0 * s0, u2y = dy0 * s0, u2z = dz0 * s0;
            float dx1 = cp.x - cc.x, dy1 = cp.y - cc.y, dz1 = cp.z - cc.z;
            float n1 = sqrtf(dx1 * dx1 + dy1 * dy1 + dz1 * dz1);
            float k1 = (n1 > 3.6f && n1 < 4.0f) ? 1.f : 0.f;
            float s1 = k1 / fmaxf(n1 * k1, 1e-12f);
            float u1x = dx1 * s1, u1y = dy1 * s1, u1z = dz1 * s1;
            float cx = u2y * u1z - u2z * u1y;
            float cy = u2z * u1x - u2x * u1z;
            float cz = u2x * u1y - u2y * u1x;
            float cn = sqrtf(cx * cx + cy * cy + cz * cz);
            float cinv = 1.f / fmaxf(cn, 1e-12f);
            float n2x = cx * cinv, n2y = cy * cinv, n2z = cz * cinv;
            float ox = u2x - u1x, oy = u2y - u1y, oz = u2z - u1z;
            float on = sqrtf(ox * ox + oy * oy + oz * oz);
            float oinv = 1.f / fmaxf(on, 1e-12f);
            float o1x = ox * oinv, o1y = oy * oinv, o1z = oz * oinv;
            o[0] = o1x; o[1] = o1y; o[2] = o1z;
            o[3] = n2x; o[4] = n2y; o[5] = n2z;
            o[6] = o1y * n2z - o1z * n2y;
            o[7] = o1z * n2x - o1x * n2z;
            o[8] = o1x * n2y - o1y * n2x;
        }
        float* dst = Of + (size_t)t * 9;
#pragma unroll
        for (int r = 0; r < 9; r++) dst[r] = o[r];
    }
}

// ---- fused: topk (tight-bounds search) -> features -> MFMA 32x128x192 -> LN ----
__global__ __launch_bounds__(256) void fused_kernel(const f32x4* __restrict__ Ca4,
                                                    const float* __restrict__ mask,
                                                    const int* __restrict__ ridx,
                                                    const int* __restrict__ chl,
                                                    const half_t* __restrict__ pwt,
                                                    const half_t* __restrict__ Bp,
                                                    const float* __restrict__ ln_g,
                                                    const float* __restrict__ ln_b,
                                                    const float* __restrict__ Of,
                                                    float* __restrict__ outE,
                                                    float* __restrict__ out_eidx_f) {
    // cand (topk phase) and featH (feature/MFMA phases) are barrier-separated -> union
    __shared__ alignas(16) char smem[32 * FROW * 2];  // 12800 B
    unsigned long long* cand = (unsigned long long*)smem;       // 512 u64 = 4096 B
    half_t(*featH)[FROW] = (half_t(*)[FROW])smem;               // 32 x 200 halves
    __shared__ int wint[2][4];
    __shared__ int gcnt[4];  // DEDICATED gather totals (reusing wint[0] races — R4/R5 bug)
    __shared__ float wflt[4];
    __shared__ unsigned wmin[4];  // block-min of dadj bits (tight search lower bound)
    __shared__ int sj[32];     // top-30 neighbor index handoff (LDS, not global)
    __shared__ float sd0[32];  // top-30 distance handoff
    __shared__ float sD[30][10];
    __shared__ float psum[32][4], pssq[32][4];
    __shared__ float rmu[32], rinv[32];

    int row = blockIdx.x;
    int b = row >> 12;
    int i = row & (LL - 1);
    int tid = threadIdx.x;
    int w = tid >> 6, lane = tid & 63;

    // ================= Phase T: top-30 =================
    float3 ci = loadCa4(Ca4, b, i);
    float mi = mask[row];
    float dreg[16];
    unsigned mfl = 0;
    float localmax = 0.f;
#pragma unroll
    for (int s = 0; s < 16; s++) {
        int j = tid + s * 256;
        f32x4 pj = Ca4[b * LL + j];
        float dx = pj[0] - ci.x, dy = pj[1] - ci.y, dz = pj[2] - ci.z;
        float d = sqrtf(dx * dx + dy * dy + dz * dz + 1e-6f);
        float m2 = mi * mask[b * LL + j];
        float D = m2 * d;
        dreg[s] = D;
        mfl |= (m2 == 0.f ? 1u : 0u) << s;
        localmax = fmaxf(localmax, D);
    }
#pragma unroll
    for (int o = 32; o; o >>= 1) localmax = fmaxf(localmax, __shfl_xor(localmax, o));
    if (lane == 0) wflt[w] = localmax;
    __syncthreads();
    float dmax = fmaxf(fmaxf(wflt[0], wflt[1]), fmaxf(wflt[2], wflt[3]));
    unsigned ui[16];
    unsigned localmin = 0xffffffffu;
#pragma unroll
    for (int s = 0; s < 16; s++) {
        unsigned u = __float_as_uint(dreg[s] + (((mfl >> s) & 1) ? dmax : 0.f));
        ui[s] = u;
        localmin = (u < localmin) ? u : localmin;
    }
#pragma unroll
    for (int o = 32; o; o >>= 1) {
        unsigned u = __shfl_xor(localmin, o);
        localmin = (u < localmin) ? u : localmin;
    }
    if (lane == 0) wmin[w] = localmin;
    __syncthreads();
    unsigned umin = min(min(wmin[0], wmin[1]), min(wmin[2], wmin[3]));
    // Tight bounds: count(<umin)==0 < 30 (safe lo); dadj_max == dmax exactly -> safe hi.
    // Cuts ~2^31 start interval to ~2^25 -> ~half the search iterations.
    unsigned lo = umin, hi = __float_as_uint(dmax) + 1u, T = 0u;
    bool found = false;
    int p = 0;
    for (int it = 0; it < 24 && !found; ++it) {
        if (hi - lo <= 1u) break;  // degenerate interval -> fallback path handles
        unsigned mid = lo + ((hi - lo) >> 1);
        int c = 0;
#pragma unroll
        for (int s = 0; s < 16; s++) c += (ui[s] < mid) ? 1 : 0;
#pragma unroll
        for (int o = 32; o; o >>= 1) c += __shfl_xor(c, o);
        if (lane == 0) wint[p][w] = c;
        __syncthreads();
        c = wint[p][0] + wint[p][1] + wint[p][2] + wint[p][3];
        p ^= 1;
        if (c < 30) lo = mid;
        else if (c > 64) hi = mid;
        else { T = mid; found = true; }
    }
    if (!found) T = hi;
    int cnt = 0;
#pragma unroll
    for (int s = 0; s < 16; s++) cnt += (ui[s] < T) ? 1 : 0;
    int inc = cnt;
#pragma unroll
    for (int o = 1; o < 64; o <<= 1) {
        int nv = __shfl_up(inc, o);
        if (lane >= o) inc += nv;
    }
    if (lane == 63) gcnt[w] = inc;
    __syncthreads();
    int C = gcnt[0] + gcnt[1] + gcnt[2] + gcnt[3];
    int waveoff = 0;
    for (int q = 0; q < 4; q++) waveoff += (q < w) ? gcnt[q] : 0;
    int slot = waveoff + inc - cnt;
#pragma unroll
    for (int s = 0; s < 16; s++) {
        if (ui[s] < T) {
            int j = tid + s * 256;
            if (slot < 512)
                cand[slot] = ((unsigned long long)ui[s] << 32) | (unsigned)j;
            slot++;
        }
    }
    __syncthreads();
    if (w == 0) {
        if (C <= 64) {
            unsigned long long v = (lane < C) ? cand[lane] : ~0ull;
#pragma unroll
            for (int k = 2; k <= 64; k <<= 1) {
#pragma unroll
                for (int jj = k >> 1; jj > 0; jj >>= 1) {
                    unsigned long long o = __shfl_xor(v, jj);
                    bool take_min = (((lane & jj) == 0) == ((lane & k) == 0));
                    bool lt = (o < v);
                    v = (take_min == lt) ? o : v;
                }
            }
            if (lane < KK) {
                int j = (int)(v & 0xffffffffu);
                sj[lane] = j;
                sd0[lane] = __uint_as_float((unsigned)(v >> 32));
                out_eidx_f[row * KK + lane] = (float)j;
            }
        } else {
            unsigned long long r[8];
#pragma unroll
            for (int q = 0; q < 8; q++) {
                int idx = lane + 64 * q;
                r[q] = (idx < C && idx < 512) ? cand[idx] : ~0ull;
            }
            for (int t = 0; t < KK; t++) {
                unsigned long long v = r[0];
#pragma unroll
                for (int q = 1; q < 8; q++) v = (r[q] < v) ? r[q] : v;
#pragma unroll
                for (int o = 32; o; o >>= 1) {
                    unsigned long long u = __shfl_xor(v, o);
                    if (u < v) v = u;
                }
                if (lane == 0) {
                    int j = (int)(v & 0xffffffffu);
                    sj[t] = j;
                    sd0[t] = __uint_as_float((unsigned)(v >> 32));
                    out_eidx_f[row * KK + t] = (float)j;
                }
#pragma unroll
                for (int q = 0; q < 8; q++)
                    if (r[q] == v) r[q] = ~0ull;
            }
        }
    }
    __syncthreads();  // cand dead beyond this point; featH (same bytes) may be written

    // ================= Phase P0: per-edge gather (2 threads/edge) =================
    if (tid < 60) {
        int e = tid >> 1, half = tid & 1;
        int j = sj[e];
        if (half == 0) {
            float3 Pi0 = shiftedCa4(Ca4, b, i, 0);
            float3 Pi2 = shiftedCa4(Ca4, b, i, 2);
            float3 Pj0 = shiftedCa4(Ca4, b, j, 0);
            float3 Pj1 = loadCa4(Ca4, b, j);
            float3 Pj2 = shiftedCa4(Ca4, b, j, 2);
            sD[e][0] = sd0[e];
            sD[e][1] = pdist(Pi0, Pj0);
            sD[e][2] = pdist(Pi2, Pj2);
            sD[e][3] = pdist(Pi0, Pj1);
            sD[e][4] = pdist(Pi0, Pj2);
            int off = ridx[row] - ridx[b * LL + j];
            int eqc = (chl[row] == chl[b * LL + j]) ? 1 : 0;
            int d = off + 32;
            d = d < 0 ? 0 : (d > 64 ? 64 : d);
            d = eqc ? d : 65;
            *(half8*)&featH[e][0] = *(const half8*)(pwt + d * 16);
            *(half8*)&featH[e][8] = *(const half8*)(pwt + d * 16 + 8);
        } else {
            float3 Pi1 = loadCa4(Ca4, b, i);
            float3 Pi2 = shiftedCa4(Ca4, b, i, 2);
            float3 Pj0 = shiftedCa4(Ca4, b, j, 0);
            float3 Pj1 = loadCa4(Ca4, b, j);
            float3 Pj2 = shiftedCa4(Ca4, b, j, 2);
            sD[e][5] = pdist(Pi1, Pj0);
            sD[e][6] = pdist(Pi1, Pj2);
            sD[e][7] = pdist(Pi2, Pj0);
            sD[e][8] = pdist(Pi2, Pj1);
            float Oi[9], Oj[9];
#pragma unroll
            for (int r = 0; r < 9; r++) {
                Oi[r] = Of[(size_t)row * 9 + r];
                Oj[r] = Of[((size_t)(b * LL + j)) * 9 + r];
            }
            float dx = Pj1.x - Pi1.x, dy = Pj1.y - Pi1.y, dz = Pj1.z - Pi1.z;
            float v0 = Oi[0] * dx + Oi[1] * dy + Oi[2] * dz;
            float v1 = Oi[3] * dx + Oi[4] * dy + Oi[5] * dz;
            float v2 = Oi[6] * dx + Oi[7] * dy + Oi[8] * dz;
            float nn = sqrtf(v0 * v0 + v1 * v1 + v2 * v2);
            float ninv = 1.f / fmaxf(nn, 1e-12f);
            float R[3][3];
#pragma unroll
            for (int m = 0; m < 3; m++)
#pragma unroll
                for (int n = 0; n < 3; n++)
                    R[m][n] = Oi[0 * 3 + m] * Oj[0 * 3 + n] + Oi[1 * 3 + m] * Oj[1 * 3 + n] +
                              Oi[2 * 3 + m] * Oj[2 * 3 + n];
            float Rxx = R[0][0], Ryy = R[1][1], Rzz = R[2][2];
            float m0 = 0.5f * sqrtf(fabsf(1.f + Rxx - Ryy - Rzz));
            float m1 = 0.5f * sqrtf(fabsf(1.f - Rxx + Ryy - Rzz));
            float m2 = 0.5f * sqrtf(fabsf(1.f - Rxx - Ryy + Rzz));
            float x = sgnf(R[2][1] - R[1][2]) * m0;
            float y = sgnf(R[0][2] - R[2][0]) * m1;
            float z = sgnf(R[1][0] - R[0][1]) * m2;
            float ww = 0.5f * sqrtf(fmaxf(1.f + Rxx + Ryy + Rzz, 0.f));
            float qn = sqrtf(x * x + y * y + z * z + ww * ww);
            float qi = 1.f / fmaxf(qn, 1e-12f);
            half8 h;
            h[0] = (half_t)(v0 * ninv);
            h[1] = (half_t)(v1 * ninv);
            h[2] = (half_t)(v2 * ninv);
            h[3] = (half_t)(x * qi);
            h[4] = (half_t)(y * qi);
            h[5] = (half_t)(z * qi);
            h[6] = (half_t)(ww * qi);
            h[7] = (half_t)0.f;
            half8 zv = {};
            *(half8*)&featH[e][160] = h;   // cols 160..167 (167 = 0)
            *(half8*)&featH[e][168] = zv;  // zero k-pad; MFMA reads up to col 192
            *(half8*)&featH[e][176] = zv;
            *(half8*)&featH[e][184] = zv;
        }
    } else if (tid >= 64 && tid < 114) {
        int t = tid - 64;  // 0..49: zero rows 30,31 (25 half8 chunks each)
        int r = 30 + t / 25, c = t % 25;
        half8 zv = {};
        *(half8*)&featH[r][c * 8] = zv;
    }
    __syncthreads();

    // ================= Phase P1: 270 uniform RBF jobs =================
    for (int job = tid; job < 270; job += 256) {
        int e = job / 9, q = job - e * 9;
        float D = sD[e][q];
        half8 v0, v1;
#pragma unroll
        for (int m = 0; m < 8; m++) {
            float mu = 2.0f + (4.f / 3.f) * (float)m;
            float t = (D - mu) * 0.8f;
            v0[m] = (half_t)exp2f(t * t * -1.4426950408889634f);
        }
#pragma unroll
        for (int m = 8; m < 16; m++) {
            float mu = 2.0f + (4.f / 3.f) * (float)m;
            float t = (D - mu) * 0.8f;
            v1[m - 8] = (half_t)exp2f(t * t * -1.4426950408889634f);
        }
        *(half8*)&featH[e][16 + 16 * q] = v0;
        *(half8*)&featH[e][24 + 16 * q] = v1;
    }
    __syncthreads();

    // ========== Phase P2: col-split MFMA — wave w owns 32 rows x cols [32w, 32w+32) ==========
    int cc = lane & 15, g = lane >> 4;
    f32x4 zero = {0.f, 0.f, 0.f, 0.f};
    f32x4 acc[2][2];
#pragma unroll
    for (int m = 0; m < 2; m++)
#pragma unroll
        for (int t = 0; t < 2; t++) acc[m][t] = zero;
    const half_t* b0p = Bp + ((size_t)(2 * w) * 6) * 64 * 8;
    const half_t* b1p = Bp + ((size_t)(2 * w + 1) * 6) * 64 * 8;
    for (int s = 0; s < 6; s++) {
        int ko = 32 * s + 8 * g;
        half8 af0 = *(const half8*)&featH[cc][ko];
        half8 af1 = *(const half8*)&featH[16 + cc][ko];
        half8 bf0 = *(const half8*)(b0p + (size_t)(s * 64 + lane) * 8);
        half8 bf1 = *(const half8*)(b1p + (size_t)(s * 64 + lane) * 8);
        acc[0][0] = __builtin_amdgcn_mfma_f32_16x16x32_f16(af0, bf0, acc[0][0], 0, 0, 0);
        acc[0][1] = __builtin_amdgcn_mfma_f32_16x16x32_f16(af0, bf1, acc[0][1], 0, 0, 0);
        acc[1][0] = __builtin_amdgcn_mfma_f32_16x16x32_f16(af1, bf0, acc[1][0], 0, 0, 0);
        acc[1][1] = __builtin_amdgcn_mfma_f32_16x16x32_f16(af1, bf1, acc[1][1], 0, 0, 0);
    }

    // ======= Phase P3: per-row LN partials within the wave's 32-col slice =======
#pragma unroll
    for (int m = 0; m < 2; m++) {
#pragma unroll
        for (int q = 0; q < 4; q++) {
            float v0 = acc[m][0][q], v1 = acc[m][1][q];
            float sp = v0 + v1;
            float qp = v0 * v0 + v1 * v1;
#pragma unroll
            for (int o = 1; o < 16; o <<= 1) {
                sp += __shfl_xor(sp, o);
                qp += __shfl_xor(qp, o);
            }
            if (cc == 0) {
                int r = 16 * m + 4 * g + q;
                psum[r][w] = sp;
                pssq[r][w] = qp;
            }
        }
    }
    __syncthreads();
    if (tid < 32) {
        float sum = psum[tid][0] + psum[tid][1] + psum[tid][2] + psum[tid][3];
        float ssq = pssq[tid][0] + pssq[tid][1] + pssq[tid][2] + pssq[tid][3];
        float mu = sum * (1.f / 128.f);
        float var = fmaxf(ssq * (1.f / 128.f) - mu * mu, 0.f);
        rmu[tid] = mu;
        rinv[tid] = 1.f / sqrtf(var + 1e-5f);
    }
    __syncthreads();

    // ================= Phase P4: normalize + store =================
    float lgv[2], lbv[2];
#pragma unroll
    for (int tt = 0; tt < 2; tt++) {
        lgv[tt] = ln_g[32 * w + 16 * tt + cc];
        lbv[tt] = ln_b[32 * w + 16 * tt + cc];
    }
#pragma unroll
    for (int m = 0; m < 2; m++) {
#pragma unroll
        for (int q = 0; q < 4; q++) {
            int r = 16 * m + 4 * g + q;
            if (r < KK) {
                float mu = rmu[r], invs = rinv[r];
                float* dst = outE + ((size_t)(row * KK + r)) * CDIM + 32 * w + cc;
                dst[0] = (acc[m][0][q] - mu) * invs * lgv[0] + lbv[0];
                dst[16] = (acc[m][1][q] - mu) * invs * lgv[1] + lbv[1];
            }
        }
    }
}

extern "C" void kernel_launch(void* const* d_in, const int* in_sizes, int n_in,
                              void* d_out, int out_size, void* d_ws, size_t ws_size,
                              hipStream_t stream) {
    const float* Ca = (const float*)d_in[0];
    const float* mask = (const float*)d_in[1];
    const int* ridx = (const int*)d_in[2];
    const int* chl = (const int*)d_in[3];
    const float* posW = (const float*)d_in[4];
    const float* posb = (const float*)d_in[5];
    const float* edgeW = (const float*)d_in[6];
    const float* lng = (const float*)d_in[7];
    const float* lnb = (const float*)d_in[8];

    float* outE = (float*)d_out;
    float* outEidxF = outE + (size_t)NB * LL * KK * CDIM;

    char* ws = (char*)d_ws;
    half_t* Bp = (half_t*)ws;                     // 49152 B
    half_t* pwt = (half_t*)(ws + 49152);          // 2112 B
    float* Of = (float*)(ws + 51264);             // 294912 B
    f32x4* Ca4 = (f32x4*)(ws + 346176);           // 131072 B

    prep_kernel<<<17 + (NB * LL + 255) / 256, 256, 0, stream>>>(edgeW, posW, posb, Ca,
                                                                Bp, pwt, Of, Ca4);
    fused_kernel<<<NB * LL, 256, 0, stream>>>(Ca4, mask, ridx, chl, pwt, Bp, lng, lnb,
                                              Of, outE, outEidxF);
}

// Round 16
// 97.293 us; speedup vs baseline: 1.4971x; 1.0781x over previous
//
#include <hip/hip_runtime.h>
#include <stdint.h>

#define LL 4096
#define NB 2
#define KK 30
#define CDIM 128
#define FROW 200  // feat row stride in halves (400 B, multiple of 16 B)

typedef _Float16 half_t;
typedef half_t half8 __attribute__((ext_vector_type(8)));
typedef float f32x4 __attribute__((ext_vector_type(4)));

__device__ __forceinline__ float3 loadCa(const float* __restrict__ Ca, int b, int idx) {
    const float* p = Ca + ((size_t)(b * LL + idx)) * 3;
    return make_float3(p[0], p[1], p[2]);
}
__device__ __forceinline__ float3 loadCa4(const f32x4* __restrict__ Ca4, int b, int idx) {
    f32x4 v = Ca4[b * LL + idx];
    return make_float3(v[0], v[1], v[2]);
}
__device__ __forceinline__ float3 shiftedCa4(const f32x4* __restrict__ Ca4, int b, int idx, int sel) {
    int jj = idx + sel - 1;
    if (jj < 0 || jj >= LL) return make_float3(0.f, 0.f, 0.f);
    return loadCa4(Ca4, b, jj);
}
__device__ __forceinline__ float sgnf(float x) { return (x > 0.f) ? 1.f : ((x < 0.f) ? -1.f : 0.f); }
__device__ __forceinline__ float pdist(float3 a, float3 c) {
    float dx = a.x - c.x, dy = a.y - c.y, dz = a.z - c.z;
    return sqrtf(dx * dx + dy * dy + dz * dz + 1e-6f);
}

// ------- prep: W pack (f16 B-frags) + posW transpose + local frames + Ca float4 copy -------
__global__ __launch_bounds__(256) void prep_kernel(const float* __restrict__ W,
                                                   const float* __restrict__ posW,
                                                   const float* __restrict__ posb,
                                                   const float* __restrict__ Ca,
                                                   half_t* __restrict__ Bp,
                                                   half_t* __restrict__ pwt,
                                                   float* __restrict__ Of,
                                                   f32x4* __restrict__ Ca4) {
    int blk = blockIdx.x;
    int tid = threadIdx.x;
    if (blk < 12) {
        // Bp[((T*6+s)*64 + l)*8 + e] = W[n=16T+(l&15)][k=32s+8*(l>>4)+e], 0 if k>=167
        int idx = blk * 256 + tid;
        if (idx >= 8 * 6 * 64) return;
        int l = idx & 63;
        int ts = idx >> 6;
        int s = ts % 6, t = ts / 6;
        int n = 16 * t + (l & 15);
        int kbase = 32 * s + 8 * (l >> 4);
        half8 v;
#pragma unroll
        for (int e = 0; e < 8; e++) {
            int k = kbase + e;
            v[e] = (k < 167) ? (half_t)W[n * 167 + k] : (half_t)0.f;
        }
        *(half8*)(Bp + (size_t)idx * 8) = v;
    } else if (blk < 17) {
        int idx = (blk - 12) * 256 + tid;
        if (idx < 66 * 16) {
            int d = idx >> 4, p = idx & 15;
            pwt[d * 16 + p] = (half_t)(posW[p * 66 + d] + posb[p]);
        }
    } else {
        int t = (blk - 17) * 256 + tid;
        if (t >= NB * LL) return;
        int b = t >> 12, i = t & (LL - 1);
        f32x4 c4;
        c4[0] = Ca[(size_t)t * 3];
        c4[1] = Ca[(size_t)t * 3 + 1];
        c4[2] = Ca[(size_t)t * 3 + 2];
        c4[3] = 0.f;
        Ca4[t] = c4;
        float o[9] = {0.f, 0.f, 0.f, 0.f, 0.f, 0.f, 0.f, 0.f, 0.f};
        if (i >= 1 && i <= LL - 3) {
            float3 cm = loadCa(Ca, b, i - 1), cc = loadCa(Ca, b, i), cp = loadCa(Ca, b, i + 1);
            float dx0 = cc.x - cm.x, dy0 = cc.y - cm.y, dz0 = cc.z - cm.z;
            float n0 = sqrtf(dx0 * dx0 + dy0 * dy0 + dz0 * dz0);
            float k0 = (n0 > 3.6f && n0 < 4.0f) ? 1.f : 0.f;
            float s0 = k0 / fmaxf(n0 * k0, 1e-12f);
            float u2x = dx0 * s0, u2y = dy0 * s0, u2z = dz0 * s0;
            float dx1 = cp.x - cc.x, dy1 = cp.y - cc.y, dz1 = cp.z - cc.z;
            float n1 = sqrtf(dx1 * dx1 + dy1 * dy1 + dz1 * dz1);
            float k1 = (n1 > 3.6f && n1 < 4.0f) ? 1.f : 0.f;
            float s1 = k1 / fmaxf(n1 * k1, 1e-12f);
            float u1x = dx1 * s1, u1y = dy1 * s1, u1z = dz1 * s1;
            float cx = u2y * u1z - u2z * u1y;
            float cy = u2z * u1x - u2x * u1z;
            float cz = u2x * u1y - u2y * u1x;
            float cn = sqrtf(cx * cx + cy * cy + cz * cz);
            float cinv = 1.f / fmaxf(cn, 1e-12f);
            float n2x = cx * cinv, n2y = cy * cinv, n2z = cz * cinv;
            float ox = u2x - u1x, oy = u2y - u1y, oz = u2z - u1z;
            float on = sqrtf(ox * ox + oy * oy + oz * oz);
            float oinv = 1.f / fmaxf(on, 1e-12f);
            float o1x = ox * oinv, o1y = oy * oinv, o1z = oz * oinv;
            o[0] = o1x; o[1] = o1y; o[2] = o1z;
            o[3] = n2x; o[4] = n2y; o[5] = n2z;
            o[6] = o1y * n2z - o1z * n2y;
            o[7] = o1z * n2x - o1x * n2z;
            o[8] = o1x * n2y - o1y * n2x;
        }
        float* dst = Of + (size_t)t * 9;
#pragma unroll
        for (int r = 0; r < 9; r++) dst[r] = o[r];
    }
}

// ---- fused: topk (tight bounds + ballot count) -> features -> MFMA -> LN ----
__global__ __launch_bounds__(256) void fused_kernel(const f32x4* __restrict__ Ca4,
                                                    const float* __restrict__ mask,
                                                    const int* __restrict__ ridx,
                                                    const int* __restrict__ chl,
                                                    const half_t* __restrict__ pwt,
                                                    const half_t* __restrict__ Bp,
                                                    const float* __restrict__ ln_g,
                                                    const float* __restrict__ ln_b,
                                                    const float* __restrict__ Of,
                                                    float* __restrict__ outE,
                                                    float* __restrict__ out_eidx_f) {
    // cand (topk phase) and featH (feature/MFMA phases) are barrier-separated -> union
    __shared__ alignas(16) char smem[32 * FROW * 2];  // 12800 B
    unsigned long long* cand = (unsigned long long*)smem;       // 512 u64 = 4096 B
    half_t(*featH)[FROW] = (half_t(*)[FROW])smem;               // 32 x 200 halves
    __shared__ int wint[2][4];
    __shared__ int gcnt[4];  // DEDICATED gather totals (reusing wint[0] races — R4/R5 bug)
    __shared__ float wflt[4];
    __shared__ unsigned wmin[4];  // block-min of dadj bits (tight search lower bound)
    __shared__ int sj[32];     // top-30 neighbor index handoff (LDS, not global)
    __shared__ float sd0[32];  // top-30 distance handoff
    __shared__ float sD[30][10];
    __shared__ float psum[32][4], pssq[32][4];
    __shared__ float rmu[32], rinv[32];

    int row = blockIdx.x;
    int b = row >> 12;
    int i = row & (LL - 1);
    int tid = threadIdx.x;
    int w = tid >> 6, lane = tid & 63;

    // ================= Phase T: top-30 =================
    float3 ci = loadCa4(Ca4, b, i);
    float mi = mask[row];
    float dreg[16];
    unsigned mfl = 0;
    float localmax = 0.f;
#pragma unroll
    for (int s = 0; s < 16; s++) {
        int j = tid + s * 256;
        f32x4 pj = Ca4[b * LL + j];
        float dx = pj[0] - ci.x, dy = pj[1] - ci.y, dz = pj[2] - ci.z;
        float d = sqrtf(dx * dx + dy * dy + dz * dz + 1e-6f);
        float m2 = mi * mask[b * LL + j];
        float D = m2 * d;
        dreg[s] = D;
        mfl |= (m2 == 0.f ? 1u : 0u) << s;
        localmax = fmaxf(localmax, D);
    }
#pragma unroll
    for (int o = 32; o; o >>= 1) localmax = fmaxf(localmax, __shfl_xor(localmax, o));
    if (lane == 0) wflt[w] = localmax;
    __syncthreads();
    float dmax = fmaxf(fmaxf(wflt[0], wflt[1]), fmaxf(wflt[2], wflt[3]));
    unsigned ui[16];
    unsigned localmin = 0xffffffffu;
#pragma unroll
    for (int s = 0; s < 16; s++) {
        unsigned u = __float_as_uint(dreg[s] + (((mfl >> s) & 1) ? dmax : 0.f));
        ui[s] = u;
        localmin = (u < localmin) ? u : localmin;
    }
#pragma unroll
    for (int o = 32; o; o >>= 1) {
        unsigned u = __shfl_xor(localmin, o);
        localmin = (u < localmin) ? u : localmin;
    }
    if (lane == 0) wmin[w] = localmin;
    __syncthreads();
    unsigned umin = min(min(wmin[0], wmin[1]), min(wmin[2], wmin[3]));
    // Tight bounds (R15-proven): count(<umin)==0 safe lo; dadj_max == dmax exactly safe hi.
    unsigned lo = umin, hi = __float_as_uint(dmax) + 1u, T = 0u;
    bool found = false;
    int p = 0;
    for (int it = 0; it < 24 && !found; ++it) {
        if (hi - lo <= 1u) break;  // degenerate interval -> fallback path handles
        unsigned mid = lo + ((hi - lo) >> 1);
        // ballot + popcount: predicate in SGPR, count on SALU — no cross-lane shuffles
        int c = 0;
#pragma unroll
        for (int s = 0; s < 16; s++)
            c += (int)__builtin_popcountll(__ballot(ui[s] < mid));
        if (lane == 0) wint[p][w] = c;
        __syncthreads();
        c = wint[p][0] + wint[p][1] + wint[p][2] + wint[p][3];
        p ^= 1;
        if (c < 30) lo = mid;
        else if (c > 64) hi = mid;
        else { T = mid; found = true; }
    }
    if (!found) T = hi;
    int cnt = 0;
#pragma unroll
    for (int s = 0; s < 16; s++) cnt += (ui[s] < T) ? 1 : 0;
    int inc = cnt;
#pragma unroll
    for (int o = 1; o < 64; o <<= 1) {
        int nv = __shfl_up(inc, o);
        if (lane >= o) inc += nv;
    }
    if (lane == 63) gcnt[w] = inc;
    __syncthreads();
    int C = gcnt[0] + gcnt[1] + gcnt[2] + gcnt[3];
    int waveoff = 0;
    for (int q = 0; q < 4; q++) waveoff += (q < w) ? gcnt[q] : 0;
    int slot = waveoff + inc - cnt;
#pragma unroll
    for (int s = 0; s < 16; s++) {
        if (ui[s] < T) {
            int j = tid + s * 256;
            if (slot < 512)
                cand[slot] = ((unsigned long long)ui[s] << 32) | (unsigned)j;
            slot++;
        }
    }
    __syncthreads();
    if (w == 0) {
        if (C <= 64) {
            unsigned long long v = (lane < C) ? cand[lane] : ~0ull;
#pragma unroll
            for (int k = 2; k <= 64; k <<= 1) {
#pragma unroll
                for (int jj = k >> 1; jj > 0; jj >>= 1) {
                    unsigned long long o = __shfl_xor(v, jj);
                    bool take_min = (((lane & jj) == 0) == ((lane & k) == 0));
                    bool lt = (o < v);
                    v = (take_min == lt) ? o : v;
                }
            }
            if (lane < KK) {
                int j = (int)(v & 0xffffffffu);
                sj[lane] = j;
                sd0[lane] = __uint_as_float((unsigned)(v >> 32));
                out_eidx_f[row * KK + lane] = (float)j;
            }
        } else {
            unsigned long long r[8];
#pragma unroll
            for (int q = 0; q < 8; q++) {
                int idx = lane + 64 * q;
                r[q] = (idx < C && idx < 512) ? cand[idx] : ~0ull;
            }
            for (int t = 0; t < KK; t++) {
                unsigned long long v = r[0];
#pragma unroll
                for (int q = 1; q < 8; q++) v = (r[q] < v) ? r[q] : v;
#pragma unroll
                for (int o = 32; o; o >>= 1) {
                    unsigned long long u = __shfl_xor(v, o);
                    if (u < v) v = u;
                }
                if (lane == 0) {
                    int j = (int)(v & 0xffffffffu);
                    sj[t] = j;
                    sd0[t] = __uint_as_float((unsigned)(v >> 32));
                    out_eidx_f[row * KK + t] = (float)j;
                }
#pragma unroll
                for (int q = 0; q < 8; q++)
                    if (r[q] == v) r[q] = ~0ull;
            }
        }
    }
    __syncthreads();  // cand dead beyond this point; featH (same bytes) may be written

    // ================= Phase P0: per-edge gather (2 threads/edge) =================
    if (tid < 60) {
        int e = tid >> 1, half = tid & 1;
        int j = sj[e];
        if (half == 0) {
            float3 Pi0 = shiftedCa4(Ca4, b, i, 0);
            float3 Pi2 = shiftedCa4(Ca4, b, i, 2);
            float3 Pj0 = shiftedCa4(Ca4, b, j, 0);
            float3 Pj1 = loadCa4(Ca4, b, j);
            float3 Pj2 = shiftedCa4(Ca4, b, j, 2);
            sD[e][0] = sd0[e];
            sD[e][1] = pdist(Pi0, Pj0);
            sD[e][2] = pdist(Pi2, Pj2);
            sD[e][3] = pdist(Pi0, Pj1);
            sD[e][4] = pdist(Pi0, Pj2);
            int off = ridx[row] - ridx[b * LL + j];
            int eqc = (chl[row] == chl[b * LL + j]) ? 1 : 0;
            int d = off + 32;
            d = d < 0 ? 0 : (d > 64 ? 64 : d);
            d = eqc ? d : 65;
            *(half8*)&featH[e][0] = *(const half8*)(pwt + d * 16);
            *(half8*)&featH[e][8] = *(const half8*)(pwt + d * 16 + 8);
        } else {
            float3 Pi1 = loadCa4(Ca4, b, i);
            float3 Pi2 = shiftedCa4(Ca4, b, i, 2);
            float3 Pj0 = shiftedCa4(Ca4, b, j, 0);
            float3 Pj1 = loadCa4(Ca4, b, j);
            float3 Pj2 = shiftedCa4(Ca4, b, j, 2);
            sD[e][5] = pdist(Pi1, Pj0);
            sD[e][6] = pdist(Pi1, Pj2);
            sD[e][7] = pdist(Pi2, Pj0);
            sD[e][8] = pdist(Pi2, Pj1);
            float Oi[9], Oj[9];
#pragma unroll
            for (int r = 0; r < 9; r++) {
                Oi[r] = Of[(size_t)row * 9 + r];
                Oj[r] = Of[((size_t)(b * LL + j)) * 9 + r];
            }
            float dx = Pj1.x - Pi1.x, dy = Pj1.y - Pi1.y, dz = Pj1.z - Pi1.z;
            float v0 = Oi[0] * dx + Oi[1] * dy + Oi[2] * dz;
            float v1 = Oi[3] * dx + Oi[4] * dy + Oi[5] * dz;
            float v2 = Oi[6] * dx + Oi[7] * dy + Oi[8] * dz;
            float nn = sqrtf(v0 * v0 + v1 * v1 + v2 * v2);
            float ninv = 1.f / fmaxf(nn, 1e-12f);
            float R[3][3];
#pragma unroll
            for (int m = 0; m < 3; m++)
#pragma unroll
                for (int n = 0; n < 3; n++)
                    R[m][n] = Oi[0 * 3 + m] * Oj[0 * 3 + n] + Oi[1 * 3 + m] * Oj[1 * 3 + n] +
                              Oi[2 * 3 + m] * Oj[2 * 3 + n];
            float Rxx = R[0][0], Ryy = R[1][1], Rzz = R[2][2];
            float m0 = 0.5f * sqrtf(fabsf(1.f + Rxx - Ryy - Rzz));
            float m1 = 0.5f * sqrtf(fabsf(1.f - Rxx + Ryy - Rzz));
            float m2 = 0.5f * sqrtf(fabsf(1.f - Rxx - Ryy + Rzz));
            float x = sgnf(R[2][1] - R[1][2]) * m0;
            float y = sgnf(R[0][2] - R[2][0]) * m1;
            float z = sgnf(R[1][0] - R[0][1]) * m2;
            float ww = 0.5f * sqrtf(fmaxf(1.f + Rxx + Ryy + Rzz, 0.f));
            float qn = sqrtf(x * x + y * y + z * z + ww * ww);
            float qi = 1.f / fmaxf(qn, 1e-12f);
            half8 h;
            h[0] = (half_t)(v0 * ninv);
            h[1] = (half_t)(v1 * ninv);
            h[2] = (half_t)(v2 * ninv);
            h[3] = (half_t)(x * qi);
            h[4] = (half_t)(y * qi);
            h[5] = (half_t)(z * qi);
            h[6] = (half_t)(ww * qi);
            h[7] = (half_t)0.f;
            half8 zv = {};
            *(half8*)&featH[e][160] = h;   // cols 160..167 (167 = 0)
            *(half8*)&featH[e][168] = zv;  // zero k-pad; MFMA reads up to col 192
            *(half8*)&featH[e][176] = zv;
            *(half8*)&featH[e][184] = zv;
        }
    } else if (tid >= 64 && tid < 114) {
        int t = tid - 64;  // 0..49: zero rows 30,31 (25 half8 chunks each)
        int r = 30 + t / 25, c = t % 25;
        half8 zv = {};
        *(half8*)&featH[r][c * 8] = zv;
    }
    __syncthreads();

    // ================= Phase P1: 270 uniform RBF jobs =================
    for (int job = tid; job < 270; job += 256) {
        int e = job / 9, q = job - e * 9;
        float D = sD[e][q];
        half8 v0, v1;
#pragma unroll
        for (int m = 0; m < 8; m++) {
            float mu = 2.0f + (4.f / 3.f) * (float)m;
            float t = (D - mu) * 0.8f;
            v0[m] = (half_t)exp2f(t * t * -1.4426950408889634f);
        }
#pragma unroll
        for (int m = 8; m < 16; m++) {
            float mu = 2.0f + (4.f / 3.f) * (float)m;
            float t = (D - mu) * 0.8f;
            v1[m - 8] = (half_t)exp2f(t * t * -1.4426950408889634f);
        }
        *(half8*)&featH[e][16 + 16 * q] = v0;
        *(half8*)&featH[e][24 + 16 * q] = v1;
    }
    __syncthreads();

    // ========== Phase P2: col-split MFMA — wave w owns 32 rows x cols [32w, 32w+32) ==========
    int cc = lane & 15, g = lane >> 4;
    f32x4 zero = {0.f, 0.f, 0.f, 0.f};
    f32x4 acc[2][2];
#pragma unroll
    for (int m = 0; m < 2; m++)
#pragma unroll
        for (int t = 0; t < 2; t++) acc[m][t] = zero;
    const half_t* b0p = Bp + ((size_t)(2 * w) * 6) * 64 * 8;
    const half_t* b1p = Bp + ((size_t)(2 * w + 1) * 6) * 64 * 8;
    for (int s = 0; s < 6; s++) {
        int ko = 32 * s + 8 * g;
        half8 af0 = *(const half8*)&featH[cc][ko];
        half8 af1 = *(const half8*)&featH[16 + cc][ko];
        half8 bf0 = *(const half8*)(b0p + (size_t)(s * 64 + lane) * 8);
        half8 bf1 = *(const half8*)(b1p + (size_t)(s * 64 + lane) * 8);
        acc[0][0] = __builtin_amdgcn_mfma_f32_16x16x32_f16(af0, bf0, acc[0][0], 0, 0, 0);
        acc[0][1] = __builtin_amdgcn_mfma_f32_16x16x32_f16(af0, bf1, acc[0][1], 0, 0, 0);
        acc[1][0] = __builtin_amdgcn_mfma_f32_16x16x32_f16(af1, bf0, acc[1][0], 0, 0, 0);
        acc[1][1] = __builtin_amdgcn_mfma_f32_16x16x32_f16(af1, bf1, acc[1][1], 0, 0, 0);
    }

    // ======= Phase P3: per-row LN partials within the wave's 32-col slice =======
#pragma unroll
    for (int m = 0; m < 2; m++) {
#pragma unroll
        for (int q = 0; q < 4; q++) {
            float v0 = acc[m][0][q], v1 = acc[m][1][q];
            float sp = v0 + v1;
            float qp = v0 * v0 + v1 * v1;
#pragma unroll
            for (int o = 1; o < 16; o <<= 1) {
                sp += __shfl_xor(sp, o);
                qp += __shfl_xor(qp, o);
            }
            if (cc == 0) {
                int r = 16 * m + 4 * g + q;
                psum[r][w] = sp;
                pssq[r][w] = qp;
            }
        }
    }
    __syncthreads();
    if (tid < 32) {
        float sum = psum[tid][0] + psum[tid][1] + psum[tid][2] + psum[tid][3];
        float ssq = pssq[tid][0] + pssq[tid][1] + pssq[tid][2] + pssq[tid][3];
        float mu = sum * (1.f / 128.f);
        float var = fmaxf(ssq * (1.f / 128.f) - mu * mu, 0.f);
        rmu[tid] = mu;
        rinv[tid] = 1.f / sqrtf(var + 1e-5f);
    }
    __syncthreads();

    // ================= Phase P4: normalize + store =================
    float lgv[2], lbv[2];
#pragma unroll
    for (int tt = 0; tt < 2; tt++) {
        lgv[tt] = ln_g[32 * w + 16 * tt + cc];
        lbv[tt] = ln_b[32 * w + 16 * tt + cc];
    }
#pragma unroll
    for (int m = 0; m < 2; m++) {
#pragma unroll
        for (int q = 0; q < 4; q++) {
            int r = 16 * m + 4 * g + q;
            if (r < KK) {
                float mu = rmu[r], invs = rinv[r];
                float* dst = outE + ((size_t)(row * KK + r)) * CDIM + 32 * w + cc;
                dst[0] = (acc[m][0][q] - mu) * invs * lgv[0] + lbv[0];
                dst[16] = (acc[m][1][q] - mu) * invs * lgv[1] + lbv[1];
            }
        }
    }
}

extern "C" void kernel_launch(void* const* d_in, const int* in_sizes, int n_in,
                              void* d_out, int out_size, void* d_ws, size_t ws_size,
                              hipStream_t stream) {
    const float* Ca = (const float*)d_in[0];
    const float* mask = (const float*)d_in[1];
    const int* ridx = (const int*)d_in[2];
    const int* chl = (const int*)d_in[3];
    const float* posW = (const float*)d_in[4];
    const float* posb = (const float*)d_in[5];
    const float* edgeW = (const float*)d_in[6];
    const float* lng = (const float*)d_in[7];
    const float* lnb = (const float*)d_in[8];

    float* outE = (float*)d_out;
    float* outEidxF = outE + (size_t)NB * LL * KK * CDIM;

    char* ws = (char*)d_ws;
    half_t* Bp = (half_t*)ws;                     // 49152 B
    half_t* pwt = (half_t*)(ws + 49152);          // 2112 B
    float* Of = (float*)(ws + 51264);             // 294912 B
    f32x4* Ca4 = (f32x4*)(ws + 346176);           // 131072 B

    prep_kernel<<<17 + (NB * LL + 255) / 256, 256, 0, stream>>>(edgeW, posW, posb, Ca,
                                                                Bp, pwt, Of, Ca4);
    fused_kernel<<<NB * LL, 256, 0, stream>>>(Ca4, mask, ridx, chl, pwt, Bp, lng, lnb,
                                              Of, outE, outEidxF);
}